// Round 2
// baseline (336.251 us; speedup 1.0000x reference)
//
#include <hip/hip_runtime.h>
#include <hip/hip_bf16.h>
#include <math.h>

#define B_ 4
#define H_ 64
#define W_ 64
#define C_ 64
#define F_ 64
#define N_ 4096

typedef __attribute__((ext_vector_type(8))) short bf16x8;
typedef __attribute__((ext_vector_type(4))) float f32x4;

static __device__ __forceinline__ short f2bf(float f){
  union { __hip_bfloat16 h; short s; } u;
  u.h = __float2bfloat16(f);
  return u.s;
}

// ---------------- conv QKV: x[B,H,W,64] -> q,k (bf16 [B,N,64]), v transposed (bf16 [B,64,N]) ----------
__global__ __launch_bounds__(256) void conv_qkv_kernel(
    const float* __restrict__ x,
    const float* __restrict__ Wk, const float* __restrict__ bk,
    const float* __restrict__ Wq, const float* __restrict__ bq,
    const float* __restrict__ Wv, const float* __restrict__ bv,
    short* __restrict__ qo, short* __restrict__ ko, short* __restrict__ vt)
{
  const int co = threadIdx.x & 63;
  int p0 = blockIdx.x * 32 + ((threadIdx.x >> 6) << 3);   // 8 consecutive pixels per thread
  p0 = __builtin_amdgcn_readfirstlane(p0);                // wave-uniform -> scalar path
  const int b  = p0 >> 12;
  const int y  = (p0 >> 6) & 63;
  const int x0 = p0 & 63;                                  // multiple of 8: never crosses a row

  float ak[8], aq[8], av[8];
  const float bkv = bk[co], bqv = bq[co], bvv = bv[co];
  #pragma unroll
  for (int p = 0; p < 8; ++p){ ak[p] = bkv; aq[p] = bqv; av[p] = bvv; }

  #pragma unroll
  for (int ky = 0; ky < 3; ++ky){
    const int yy = y + ky - 1;
    if (yy < 0 || yy >= H_) continue;
    const float* xrow = x + (size_t)((b * H_ + yy) * W_) * C_;
    for (int ci = 0; ci < C_; ++ci){
      float xv[10];
      #pragma unroll
      for (int t = 0; t < 10; ++t){
        const int xx = x0 - 1 + t;
        xv[t] = (xx >= 0 && xx < W_) ? xrow[xx * C_ + ci] : 0.f;  // zero-pad SAME
      }
      #pragma unroll
      for (int kx = 0; kx < 3; ++kx){
        const int wi = (((ky * 3 + kx) * C_) + ci) * F_ + co;
        const float wkv = Wk[wi];
        const float wqv = Wq[wi];
        const float wvv = Wv[wi];
        #pragma unroll
        for (int p = 0; p < 8; ++p){
          const float xvv = xv[p + kx];
          ak[p] = fmaf(xvv, wkv, ak[p]);
          aq[p] = fmaf(xvv, wqv, aq[p]);
          av[p] = fmaf(xvv, wvv, av[p]);
        }
      }
    }
  }
  const int n0 = p0 & (N_ - 1);
  bf16x8 vpack;
  #pragma unroll
  for (int p = 0; p < 8; ++p){
    const int idx = (p0 + p) * F_ + co;
    const float ke = ak[p] > 0.f ? ak[p] : expm1f(ak[p]);  // elu
    const float qe = aq[p] > 0.f ? aq[p] : expm1f(aq[p]);  // elu
    ko[idx] = f2bf(ke);
    qo[idx] = f2bf(qe);
    vpack[p] = f2bf(av[p] > 0.f ? av[p] : 0.f);            // relu
  }
  // v transposed: vt[b][co][n0..n0+8)  (16B aligned store)
  *(bf16x8*)(vt + ((size_t)(b * F_ + co) * N_ + n0)) = vpack;
}

// ---------------- flash attention: S = QK^T * (1-I)/8, softmax, O = P V ----------------
__global__ __launch_bounds__(256) void attn_kernel(
    const short* __restrict__ q, const short* __restrict__ k,
    const short* __restrict__ vt, float* __restrict__ o)
{
  const int lane = threadIdx.x & 63;
  const int wv   = threadIdx.x >> 6;
  const int lrow = lane & 15;    // A-frag row / B-frag col / C-frag col
  const int lkb  = lane >> 4;    // k-block (input frags) / row-block (C frag)
  const int b    = blockIdx.x >> 6;
  const int rbase = ((blockIdx.x & 63) << 6) + (wv << 4);  // this wave's 16 rows

  const short* qb = q  + (size_t)b * N_ * F_;
  const short* kb = k  + (size_t)b * N_ * F_;
  const short* vb = vt + (size_t)b * F_ * N_;

  // Q fragments: lane holds Q[rbase+lrow, fc*32 + lkb*8 + j], j=0..7 (contiguous)
  const bf16x8 aq0 = *(const bf16x8*)(qb + (rbase + lrow) * F_ + lkb * 8);
  const bf16x8 aq1 = *(const bf16x8*)(qb + (rbase + lrow) * F_ + 32 + lkb * 8);

  float m_r[4], l_r[4];
  f32x4 oacc[4];
  #pragma unroll
  for (int i = 0; i < 4; ++i){ m_r[i] = -INFINITY; l_r[i] = 0.f; }
  #pragma unroll
  for (int fs = 0; fs < 4; ++fs){
    #pragma unroll
    for (int i = 0; i < 4; ++i) oacc[fs][i] = 0.f;
  }

  __shared__ short p_lds[4][16][80];   // pad 64->80: breaks 16-way row conflict, keeps 16B align
  short (*pl)[80] = p_lds[wv];         // wave-private: no barriers needed

  for (int ct = 0; ct < N_ / 64; ++ct){
    const int cbase = ct << 6;
    // ---- S = Q K^T for 64 columns (4 sub-tiles of 16) ----
    f32x4 s[4];
    #pragma unroll
    for (int n = 0; n < 4; ++n){
      #pragma unroll
      for (int i = 0; i < 4; ++i) s[n][i] = 0.f;
    }
    #pragma unroll
    for (int n = 0; n < 4; ++n){
      const short* krow = kb + (cbase + n * 16 + lrow) * F_;
      const bf16x8 b0 = *(const bf16x8*)(krow + lkb * 8);
      const bf16x8 b1 = *(const bf16x8*)(krow + 32 + lkb * 8);
      s[n] = __builtin_amdgcn_mfma_f32_16x16x32_bf16(aq0, b0, s[n], 0, 0, 0);
      s[n] = __builtin_amdgcn_mfma_f32_16x16x32_bf16(aq1, b1, s[n], 0, 0, 0);
    }
    // ---- mask diagonal to 0 (NOT -inf), scale 1/8; per-row tile max ----
    float tmax[4];
    #pragma unroll
    for (int i = 0; i < 4; ++i) tmax[i] = -INFINITY;
    #pragma unroll
    for (int n = 0; n < 4; ++n){
      const int gc = cbase + n * 16 + lrow;
      #pragma unroll
      for (int i = 0; i < 4; ++i){
        float svv = s[n][i] * 0.125f;
        if (rbase + lkb * 4 + i == gc) svv = 0.f;
        s[n][i] = svv;
        tmax[i] = fmaxf(tmax[i], svv);
      }
    }
    #pragma unroll
    for (int i = 0; i < 4; ++i){
      #pragma unroll
      for (int d = 1; d < 16; d <<= 1)
        tmax[i] = fmaxf(tmax[i], __shfl_xor(tmax[i], d, 64));
    }
    // ---- online softmax update ----
    float pr[4][4], sc[4];
    #pragma unroll
    for (int i = 0; i < 4; ++i){
      const float mn = fmaxf(m_r[i], tmax[i]);
      sc[i] = __expf(m_r[i] - mn);   // exp(-inf)=0 on first tile
      m_r[i] = mn;
      float ps = 0.f;
      #pragma unroll
      for (int n = 0; n < 4; ++n){
        const float pv = __expf(s[n][i] - mn);
        pr[n][i] = pv;
        ps += pv;
      }
      #pragma unroll
      for (int d = 1; d < 16; d <<= 1) ps += __shfl_xor(ps, d, 64);
      l_r[i] = l_r[i] * sc[i] + ps;
    }
    #pragma unroll
    for (int fs = 0; fs < 4; ++fs){
      #pragma unroll
      for (int i = 0; i < 4; ++i) oacc[fs][i] *= sc[i];
    }
    // ---- P: C-layout -> A-layout via wave-private LDS ----
    #pragma unroll
    for (int n = 0; n < 4; ++n){
      #pragma unroll
      for (int i = 0; i < 4; ++i)
        pl[lkb * 4 + i][n * 16 + lrow] = f2bf(pr[n][i]);
    }
    const bf16x8 pa0 = *(const bf16x8*)(&pl[lrow][lkb * 8]);
    const bf16x8 pa1 = *(const bf16x8*)(&pl[lrow][32 + lkb * 8]);
    // ---- O += P V (V read from transposed layout: 16B contiguous per lane) ----
    #pragma unroll
    for (int kc = 0; kc < 2; ++kc){
      const bf16x8 pa = kc ? pa1 : pa0;
      #pragma unroll
      for (int fs = 0; fs < 4; ++fs){
        const bf16x8 bvf = *(const bf16x8*)(vb + (size_t)(fs * 16 + lrow) * N_ + cbase + kc * 32 + lkb * 8);
        oacc[fs] = __builtin_amdgcn_mfma_f32_16x16x32_bf16(pa, bvf, oacc[fs], 0, 0, 0);
      }
    }
  }
  // ---- normalize + store fp32 [B,N,F] ----
  #pragma unroll
  for (int i = 0; i < 4; ++i){
    const float inv = 1.f / l_r[i];
    const size_t rowoff = ((size_t)b * N_ + rbase + lkb * 4 + i) * F_;
    #pragma unroll
    for (int fs = 0; fs < 4; ++fs)
      o[rowoff + fs * 16 + lrow] = oacc[fs][i] * inv;
  }
}

// ---------------- final conv: relu(conv(attn_out, Wr) + br) -> d_out fp32 ----------------
__global__ __launch_bounds__(256) void conv_out_kernel(
    const float* __restrict__ xin,
    const float* __restrict__ Wr, const float* __restrict__ br,
    float* __restrict__ out)
{
  const int co = threadIdx.x & 63;
  int p0 = blockIdx.x * 32 + ((threadIdx.x >> 6) << 3);
  p0 = __builtin_amdgcn_readfirstlane(p0);
  const int b  = p0 >> 12;
  const int y  = (p0 >> 6) & 63;
  const int x0 = p0 & 63;

  float acc[8];
  const float bb = br[co];
  #pragma unroll
  for (int p = 0; p < 8; ++p) acc[p] = bb;

  #pragma unroll
  for (int ky = 0; ky < 3; ++ky){
    const int yy = y + ky - 1;
    if (yy < 0 || yy >= H_) continue;
    const float* xrow = xin + (size_t)((b * H_ + yy) * W_) * F_;
    for (int ci = 0; ci < F_; ++ci){
      float xv[10];
      #pragma unroll
      for (int t = 0; t < 10; ++t){
        const int xx = x0 - 1 + t;
        xv[t] = (xx >= 0 && xx < W_) ? xrow[xx * F_ + ci] : 0.f;
      }
      #pragma unroll
      for (int kx = 0; kx < 3; ++kx){
        const float wv_ = Wr[(((ky * 3 + kx) * F_) + ci) * F_ + co];
        #pragma unroll
        for (int p = 0; p < 8; ++p)
          acc[p] = fmaf(xv[p + kx], wv_, acc[p]);
      }
    }
  }
  #pragma unroll
  for (int p = 0; p < 8; ++p)
    out[(size_t)(p0 + p) * F_ + co] = fmaxf(acc[p], 0.f);
}

extern "C" void kernel_launch(void* const* d_in, const int* in_sizes, int n_in,
                              void* d_out, int out_size, void* d_ws, size_t ws_size,
                              hipStream_t stream)
{
  const float* x  = (const float*)d_in[0];
  const float* Wk = (const float*)d_in[1];
  const float* bk = (const float*)d_in[2];
  const float* Wq = (const float*)d_in[3];
  const float* bq = (const float*)d_in[4];
  const float* Wv = (const float*)d_in[5];
  const float* bv = (const float*)d_in[6];
  const float* Wr = (const float*)d_in[7];
  const float* br = (const float*)d_in[8];
  float* out = (float*)d_out;

  // workspace: q (2MB bf16) | k (2MB) | v^T (2MB) | attn_out (4MB fp32) = 10MB
  short* qw = (short*)d_ws;
  short* kw = qw + (size_t)B_ * N_ * F_;
  short* vt = kw + (size_t)B_ * N_ * F_;
  float* attn = (float*)(vt + (size_t)B_ * N_ * F_);

  hipLaunchKernelGGL(conv_qkv_kernel, dim3(512), dim3(256), 0, stream,
                     x, Wk, bk, Wq, bq, Wv, bv, qw, kw, vt);
  hipLaunchKernelGGL(attn_kernel, dim3(256), dim3(256), 0, stream,
                     qw, kw, vt, attn);
  hipLaunchKernelGGL(conv_out_kernel, dim3(512), dim3(256), 0, stream,
                     attn, Wr, br, out);
}

// Round 6
// 310.113 us; speedup vs baseline: 1.0843x; 1.0843x over previous
//
#include <hip/hip_runtime.h>
#include <hip/hip_bf16.h>
#include <math.h>

#define B_ 4
#define H_ 64
#define W_ 64
#define C_ 64
#define F_ 64
#define N_ 4096

typedef __attribute__((ext_vector_type(8))) short bf16x8;
typedef __attribute__((ext_vector_type(4))) short bf16x4;
typedef __attribute__((ext_vector_type(4))) float f32x4;

static __device__ __forceinline__ short f2bf(float f){
  union { __hip_bfloat16 h; short s; } u;
  u.h = __float2bfloat16(f);
  return u.s;
}

// ---------------- conv QKV: x[B,H,W,64] -> q,k (bf16 [B,N,64]), v transposed (bf16 [B,64,N]) ----------
// 4 pixels/thread: grid 1024 blocks -> 4 waves/SIMD for latency hiding.
__global__ __launch_bounds__(256) void conv_qkv_kernel(
    const float* __restrict__ x,
    const float* __restrict__ Wk, const float* __restrict__ bk,
    const float* __restrict__ Wq, const float* __restrict__ bq,
    const float* __restrict__ Wv, const float* __restrict__ bv,
    short* __restrict__ qo, short* __restrict__ ko, short* __restrict__ vt)
{
  const int co = threadIdx.x & 63;
  int p0 = blockIdx.x * 16 + ((threadIdx.x >> 6) << 2);   // 4 consecutive pixels per thread
  p0 = __builtin_amdgcn_readfirstlane(p0);                // wave-uniform -> scalar path
  const int b  = p0 >> 12;
  const int y  = (p0 >> 6) & 63;
  const int x0 = p0 & 63;                                  // multiple of 4: never crosses a row

  float ak[4], aq[4], av[4];
  const float bkv = bk[co], bqv = bq[co], bvv = bv[co];
  #pragma unroll
  for (int p = 0; p < 4; ++p){ ak[p] = bkv; aq[p] = bqv; av[p] = bvv; }

  #pragma unroll
  for (int ky = 0; ky < 3; ++ky){
    const int yy = y + ky - 1;
    if (yy < 0 || yy >= H_) continue;
    const float* xrow = x + (size_t)((b * H_ + yy) * W_) * C_;
    for (int ci = 0; ci < C_; ++ci){
      float xv[6];
      #pragma unroll
      for (int t = 0; t < 6; ++t){
        const int xx = x0 - 1 + t;
        xv[t] = (xx >= 0 && xx < W_) ? xrow[xx * C_ + ci] : 0.f;  // zero-pad SAME
      }
      #pragma unroll
      for (int kx = 0; kx < 3; ++kx){
        const int wi = (((ky * 3 + kx) * C_) + ci) * F_ + co;
        const float wkv = Wk[wi];
        const float wqv = Wq[wi];
        const float wvv = Wv[wi];
        #pragma unroll
        for (int p = 0; p < 4; ++p){
          const float xvv = xv[p + kx];
          ak[p] = fmaf(xvv, wkv, ak[p]);
          aq[p] = fmaf(xvv, wqv, aq[p]);
          av[p] = fmaf(xvv, wvv, av[p]);
        }
      }
    }
  }
  const int n0 = p0 & (N_ - 1);
  bf16x4 vpack;
  #pragma unroll
  for (int p = 0; p < 4; ++p){
    const int idx = (p0 + p) * F_ + co;
    const float ke = ak[p] > 0.f ? ak[p] : expm1f(ak[p]);  // elu
    const float qe = aq[p] > 0.f ? aq[p] : expm1f(aq[p]);  // elu
    ko[idx] = f2bf(ke);
    qo[idx] = f2bf(qe);
    vpack[p] = f2bf(av[p] > 0.f ? av[p] : 0.f);            // relu
  }
  // v transposed: vt[b][co][n0..n0+4)  (8B aligned store)
  *(bf16x4*)(vt + ((size_t)(b * F_ + co) * N_ + n0)) = vpack;
}

// ---------------- flash attention (column-split): partial O (unnormalized) + m,l per row ----------------
__global__ __launch_bounds__(256) void attn_kernel(
    const short* __restrict__ q, const short* __restrict__ k,
    const short* __restrict__ vt, float* __restrict__ Op,
    float* __restrict__ mp, float* __restrict__ lp, int split)
{
  const int lane = threadIdx.x & 63;
  const int wv   = threadIdx.x >> 6;
  const int lrow = lane & 15;    // A-frag row / B-frag col / C-frag col
  const int lkb  = lane >> 4;    // k-block (input frags) / row-block (C frag)

  const int bid  = blockIdx.x;
  const int b    = bid / (64 * split);
  const int rem  = bid % (64 * split);
  const int rt   = rem / split;          // row tile (64 rows)
  const int sp   = rem % split;          // column split index
  const int rbase = (rt << 6) + (wv << 4);  // this wave's 16 rows
  const int tiles = (N_ / 64) / split;      // 64-col tiles per block
  const int ct0   = sp * tiles;

  const short* qb = q  + (size_t)b * N_ * F_;
  const short* kb = k  + (size_t)b * N_ * F_;
  const short* vb = vt + (size_t)b * F_ * N_;

  // Q fragments: lane holds Q[rbase+lrow, fc*32 + lkb*8 + j], j=0..7 (contiguous)
  const bf16x8 aq0 = *(const bf16x8*)(qb + (rbase + lrow) * F_ + lkb * 8);
  const bf16x8 aq1 = *(const bf16x8*)(qb + (rbase + lrow) * F_ + 32 + lkb * 8);

  float m_r[4], l_r[4];
  f32x4 oacc[4];
  #pragma unroll
  for (int i = 0; i < 4; ++i){ m_r[i] = -INFINITY; l_r[i] = 0.f; }
  #pragma unroll
  for (int fs = 0; fs < 4; ++fs){
    #pragma unroll
    for (int i = 0; i < 4; ++i) oacc[fs][i] = 0.f;
  }

  __shared__ short p_lds[4][16][80];   // pad 64->80 keeps 16B align
  short (*pl)[80] = p_lds[wv];         // wave-private: no barriers needed

  for (int t = 0; t < tiles; ++t){
    const int cbase = (ct0 + t) << 6;
    // ---- S = Q K^T for 64 columns (4 sub-tiles of 16) ----
    f32x4 s[4];
    #pragma unroll
    for (int n = 0; n < 4; ++n){
      #pragma unroll
      for (int i = 0; i < 4; ++i) s[n][i] = 0.f;
    }
    #pragma unroll
    for (int n = 0; n < 4; ++n){
      const short* krow = kb + (cbase + n * 16 + lrow) * F_;
      const bf16x8 b0 = *(const bf16x8*)(krow + lkb * 8);
      const bf16x8 b1 = *(const bf16x8*)(krow + 32 + lkb * 8);
      s[n] = __builtin_amdgcn_mfma_f32_16x16x32_bf16(aq0, b0, s[n], 0, 0, 0);
      s[n] = __builtin_amdgcn_mfma_f32_16x16x32_bf16(aq1, b1, s[n], 0, 0, 0);
    }
    // ---- mask diagonal to 0 (NOT -inf), scale 1/8; per-row tile max ----
    float tmax[4];
    #pragma unroll
    for (int i = 0; i < 4; ++i) tmax[i] = -INFINITY;
    #pragma unroll
    for (int n = 0; n < 4; ++n){
      const int gc = cbase + n * 16 + lrow;
      #pragma unroll
      for (int i = 0; i < 4; ++i){
        float svv = s[n][i] * 0.125f;
        if (rbase + lkb * 4 + i == gc) svv = 0.f;
        s[n][i] = svv;
        tmax[i] = fmaxf(tmax[i], svv);
      }
    }
    #pragma unroll
    for (int i = 0; i < 4; ++i){
      #pragma unroll
      for (int d = 1; d < 16; d <<= 1)
        tmax[i] = fmaxf(tmax[i], __shfl_xor(tmax[i], d, 64));
    }
    // ---- online softmax update ----
    float pr[4][4], sc[4];
    #pragma unroll
    for (int i = 0; i < 4; ++i){
      const float mn = fmaxf(m_r[i], tmax[i]);
      sc[i] = __expf(m_r[i] - mn);   // exp(-inf)=0 on first tile
      m_r[i] = mn;
      float ps = 0.f;
      #pragma unroll
      for (int n = 0; n < 4; ++n){
        const float pv = __expf(s[n][i] - mn);
        pr[n][i] = pv;
        ps += pv;
      }
      #pragma unroll
      for (int d = 1; d < 16; d <<= 1) ps += __shfl_xor(ps, d, 64);
      l_r[i] = l_r[i] * sc[i] + ps;
    }
    #pragma unroll
    for (int fs = 0; fs < 4; ++fs){
      #pragma unroll
      for (int i = 0; i < 4; ++i) oacc[fs][i] *= sc[i];
    }
    // ---- P: C-layout -> A-layout via wave-private LDS ----
    #pragma unroll
    for (int n = 0; n < 4; ++n){
      #pragma unroll
      for (int i = 0; i < 4; ++i)
        pl[lkb * 4 + i][n * 16 + lrow] = f2bf(pr[n][i]);
    }
    const bf16x8 pa0 = *(const bf16x8*)(&pl[lrow][lkb * 8]);
    const bf16x8 pa1 = *(const bf16x8*)(&pl[lrow][32 + lkb * 8]);
    // ---- O += P V (V read from transposed layout: 16B contiguous per lane) ----
    #pragma unroll
    for (int kc = 0; kc < 2; ++kc){
      const bf16x8 pa = kc ? pa1 : pa0;
      #pragma unroll
      for (int fs = 0; fs < 4; ++fs){
        const bf16x8 bvf = *(const bf16x8*)(vb + (size_t)(fs * 16 + lrow) * N_ + cbase + kc * 32 + lkb * 8);
        oacc[fs] = __builtin_amdgcn_mfma_f32_16x16x32_bf16(pa, bvf, oacc[fs], 0, 0, 0);
      }
    }
  }
  // ---- store UNNORMALIZED partial O + (m, l) per row ----
  float* Ob = Op + (size_t)(b * split + sp) * N_ * F_;
  #pragma unroll
  for (int i = 0; i < 4; ++i){
    const int row = rbase + lkb * 4 + i;
    #pragma unroll
    for (int fs = 0; fs < 4; ++fs)
      Ob[(size_t)row * F_ + fs * 16 + lrow] = oacc[fs][i];
    if (lrow == 0){
      mp[(size_t)(b * split + sp) * N_ + row] = m_r[i];
      lp[(size_t)(b * split + sp) * N_ + row] = l_r[i];
    }
  }
}

// ---------------- combine partials: O = (sum_s Op*exp(m_s-gm)) / (sum_s l_s*exp(m_s-gm)) ----------------
__global__ __launch_bounds__(256) void combine_kernel(
    const float* __restrict__ Op, const float* __restrict__ mp,
    const float* __restrict__ lp, float* __restrict__ o, int split)
{
  const int gid = blockIdx.x * 256 + threadIdx.x;   // over B*N*F
  const int f = gid & 63;
  const int n = (gid >> 6) & (N_ - 1);
  const int b = gid >> 18;
  float gm = -INFINITY;
  for (int s = 0; s < split; ++s)
    gm = fmaxf(gm, mp[(size_t)(b * split + s) * N_ + n]);
  float L = 0.f, O = 0.f;
  for (int s = 0; s < split; ++s){
    const float w = __expf(mp[(size_t)(b * split + s) * N_ + n] - gm);
    L += lp[(size_t)(b * split + s) * N_ + n] * w;
    O += Op[((size_t)(b * split + s) * N_ + n) * F_ + f] * w;
  }
  o[gid] = O / L;
}

// ---------------- final conv: relu(conv(attn_out, Wr) + br) -> d_out fp32 ----------------
__global__ __launch_bounds__(256) void conv_out_kernel(
    const float* __restrict__ xin,
    const float* __restrict__ Wr, const float* __restrict__ br,
    float* __restrict__ out)
{
  const int co = threadIdx.x & 63;
  int p0 = blockIdx.x * 32 + ((threadIdx.x >> 6) << 3);
  p0 = __builtin_amdgcn_readfirstlane(p0);
  const int b  = p0 >> 12;
  const int y  = (p0 >> 6) & 63;
  const int x0 = p0 & 63;

  float acc[8];
  const float bb = br[co];
  #pragma unroll
  for (int p = 0; p < 8; ++p) acc[p] = bb;

  #pragma unroll
  for (int ky = 0; ky < 3; ++ky){
    const int yy = y + ky - 1;
    if (yy < 0 || yy >= H_) continue;
    const float* xrow = xin + (size_t)((b * H_ + yy) * W_) * F_;
    for (int ci = 0; ci < F_; ++ci){
      float xv[10];
      #pragma unroll
      for (int t = 0; t < 10; ++t){
        const int xx = x0 - 1 + t;
        xv[t] = (xx >= 0 && xx < W_) ? xrow[xx * F_ + ci] : 0.f;
      }
      #pragma unroll
      for (int kx = 0; kx < 3; ++kx){
        const float wv_ = Wr[(((ky * 3 + kx) * F_) + ci) * F_ + co];
        #pragma unroll
        for (int p = 0; p < 8; ++p)
          acc[p] = fmaf(xv[p + kx], wv_, acc[p]);
      }
    }
  }
  #pragma unroll
  for (int p = 0; p < 8; ++p)
    out[(size_t)(p0 + p) * F_ + co] = fmaxf(acc[p], 0.f);
}

extern "C" void kernel_launch(void* const* d_in, const int* in_sizes, int n_in,
                              void* d_out, int out_size, void* d_ws, size_t ws_size,
                              hipStream_t stream)
{
  const float* x  = (const float*)d_in[0];
  const float* Wk = (const float*)d_in[1];
  const float* bk = (const float*)d_in[2];
  const float* Wq = (const float*)d_in[3];
  const float* bq = (const float*)d_in[4];
  const float* Wv = (const float*)d_in[5];
  const float* bv = (const float*)d_in[6];
  const float* Wr = (const float*)d_in[7];
  const float* br = (const float*)d_in[8];
  float* out = (float*)d_out;

  const size_t BNF = (size_t)B_ * N_ * F_;       // 1,048,576 elements
  // fixed ws: q,k,vt (bf16) + attn (fp32) = 10 MB
  const size_t fixed_bytes = BNF * 2 * 3 + BNF * 4;
  int split = 8;
  while (split > 1 &&
         fixed_bytes + (size_t)split * (BNF * 4 + 2 * (size_t)B_ * N_ * 4) > ws_size)
    split >>= 1;

  short* qw = (short*)d_ws;
  short* kw = qw + BNF;
  short* vt = kw + BNF;
  float* attn = (float*)(vt + BNF);
  float* Op = attn + BNF;
  float* mp = Op + (size_t)split * BNF;
  float* lp = mp + (size_t)split * B_ * N_;

  hipLaunchKernelGGL(conv_qkv_kernel, dim3(1024), dim3(256), 0, stream,
                     x, Wk, bk, Wq, bq, Wv, bv, qw, kw, vt);
  hipLaunchKernelGGL(attn_kernel, dim3(B_ * 64 * split), dim3(256), 0, stream,
                     qw, kw, vt, Op, mp, lp, split);
  hipLaunchKernelGGL(combine_kernel, dim3((B_ * N_ * F_) / 256), dim3(256), 0, stream,
                     Op, mp, lp, attn, split);
  hipLaunchKernelGGL(conv_out_kernel, dim3(512), dim3(256), 0, stream,
                     attn, Wr, br, out);
}

// Round 7
// 309.800 us; speedup vs baseline: 1.0854x; 1.0010x over previous
//
#include <hip/hip_runtime.h>
#include <hip/hip_bf16.h>
#include <math.h>

#define B_ 4
#define H_ 64
#define W_ 64
#define C_ 64
#define F_ 64
#define N_ 4096

typedef __attribute__((ext_vector_type(8))) short bf16x8;
typedef __attribute__((ext_vector_type(4))) short bf16x4;
typedef __attribute__((ext_vector_type(4))) float f32x4;

static __device__ __forceinline__ short f2bf(float f){
  union { __hip_bfloat16 h; short s; } u;
  u.h = __float2bfloat16(f);
  return u.s;
}

// ---------------- conv QKV: x[B,H,W,64] -> q,k (bf16 [B,N,64]), v transposed (bf16 [B,64,N]) ----------
__global__ __launch_bounds__(256) void conv_qkv_kernel(
    const float* __restrict__ x,
    const float* __restrict__ Wk, const float* __restrict__ bk,
    const float* __restrict__ Wq, const float* __restrict__ bq,
    const float* __restrict__ Wv, const float* __restrict__ bv,
    short* __restrict__ qo, short* __restrict__ ko, short* __restrict__ vt)
{
  const int co = threadIdx.x & 63;
  int p0 = blockIdx.x * 16 + ((threadIdx.x >> 6) << 2);   // 4 consecutive pixels per thread
  p0 = __builtin_amdgcn_readfirstlane(p0);                // wave-uniform -> scalar path
  const int b  = p0 >> 12;
  const int y  = (p0 >> 6) & 63;
  const int x0 = p0 & 63;                                  // multiple of 4: never crosses a row

  float ak[4], aq[4], av[4];
  const float bkv = bk[co], bqv = bq[co], bvv = bv[co];
  #pragma unroll
  for (int p = 0; p < 4; ++p){ ak[p] = bkv; aq[p] = bqv; av[p] = bvv; }

  #pragma unroll
  for (int ky = 0; ky < 3; ++ky){
    const int yy = y + ky - 1;
    if (yy < 0 || yy >= H_) continue;
    const float* xrow = x + (size_t)((b * H_ + yy) * W_) * C_;
    for (int ci = 0; ci < C_; ++ci){
      float xv[6];
      #pragma unroll
      for (int t = 0; t < 6; ++t){
        const int xx = x0 - 1 + t;
        xv[t] = (xx >= 0 && xx < W_) ? xrow[xx * C_ + ci] : 0.f;  // zero-pad SAME
      }
      #pragma unroll
      for (int kx = 0; kx < 3; ++kx){
        const int wi = (((ky * 3 + kx) * C_) + ci) * F_ + co;
        const float wkv = Wk[wi];
        const float wqv = Wq[wi];
        const float wvv = Wv[wi];
        #pragma unroll
        for (int p = 0; p < 4; ++p){
          const float xvv = xv[p + kx];
          ak[p] = fmaf(xvv, wkv, ak[p]);
          aq[p] = fmaf(xvv, wqv, aq[p]);
          av[p] = fmaf(xvv, wvv, av[p]);
        }
      }
    }
  }
  const int n0 = p0 & (N_ - 1);
  bf16x4 vpack;
  #pragma unroll
  for (int p = 0; p < 4; ++p){
    const int idx = (p0 + p) * F_ + co;
    const float ke = ak[p] > 0.f ? ak[p] : expm1f(ak[p]);  // elu
    const float qe = aq[p] > 0.f ? aq[p] : expm1f(aq[p]);  // elu
    ko[idx] = f2bf(ke);
    qo[idx] = f2bf(qe);
    vpack[p] = f2bf(av[p] > 0.f ? av[p] : 0.f);            // relu
  }
  *(bf16x4*)(vt + ((size_t)(b * F_ + co) * N_ + n0)) = vpack;
}

// ---------------- flash attention (column-split, defer-max, lazy l-reduce) ----------------
__global__ __launch_bounds__(256, 4) void attn_kernel(
    const short* __restrict__ q, const short* __restrict__ k,
    const short* __restrict__ vt, float* __restrict__ Op,
    float* __restrict__ mp, float* __restrict__ lp, int split)
{
  const int lane = threadIdx.x & 63;
  const int wv   = threadIdx.x >> 6;
  const int lrow = lane & 15;    // A-frag row / B-frag col / C-frag col
  const int lkb  = lane >> 4;    // k-block (input frags) / row-block (C frag)

  const int bid  = blockIdx.x;
  const int b    = bid / (64 * split);
  const int rem  = bid % (64 * split);
  const int rt   = rem / split;          // row tile (64 rows)
  const int sp   = rem % split;          // column split index
  const int rbase = (rt << 6) + (wv << 4);  // this wave's 16 rows
  const int tiles = (N_ / 64) / split;      // 64-col tiles per block
  const int ct0   = sp * tiles;

  const short* qb = q  + (size_t)b * N_ * F_;
  const short* kb = k  + (size_t)b * N_ * F_;
  const short* vb = vt + (size_t)b * F_ * N_;

  const bf16x8 aq0 = *(const bf16x8*)(qb + (rbase + lrow) * F_ + lkb * 8);
  const bf16x8 aq1 = *(const bf16x8*)(qb + (rbase + lrow) * F_ + 32 + lkb * 8);

  float m_r[4], l_r[4];       // m: per-row running max; l: PER-LANE partial sum (reduced at end)
  f32x4 oacc[4];
  #pragma unroll
  for (int i = 0; i < 4; ++i){ m_r[i] = -INFINITY; l_r[i] = 0.f; }
  #pragma unroll
  for (int fs = 0; fs < 4; ++fs){
    #pragma unroll
    for (int i = 0; i < 4; ++i) oacc[fs][i] = 0.f;
  }

  __shared__ short p_lds[4][16][80];
  short (*pl)[80] = p_lds[wv];         // wave-private: no barriers needed

  for (int t = 0; t < tiles; ++t){
    const int cbase = (ct0 + t) << 6;
    // ---- S = Q K^T for 64 columns ----
    f32x4 s[4];
    #pragma unroll
    for (int n = 0; n < 4; ++n){
      #pragma unroll
      for (int i = 0; i < 4; ++i) s[n][i] = 0.f;
    }
    #pragma unroll
    for (int n = 0; n < 4; ++n){
      const short* krow = kb + (cbase + n * 16 + lrow) * F_;
      const bf16x8 b0 = *(const bf16x8*)(krow + lkb * 8);
      const bf16x8 b1 = *(const bf16x8*)(krow + 32 + lkb * 8);
      s[n] = __builtin_amdgcn_mfma_f32_16x16x32_bf16(aq0, b0, s[n], 0, 0, 0);
      s[n] = __builtin_amdgcn_mfma_f32_16x16x32_bf16(aq1, b1, s[n], 0, 0, 0);
    }
    // ---- prefetch V for this tile (independent of softmax) ----
    bf16x8 bvf[2][4];
    #pragma unroll
    for (int kc = 0; kc < 2; ++kc)
      #pragma unroll
      for (int fs = 0; fs < 4; ++fs)
        bvf[kc][fs] = *(const bf16x8*)(vb + (size_t)(fs * 16 + lrow) * N_ + cbase + kc * 32 + lkb * 8);

    // ---- mask diagonal to 0 (NOT -inf), scale 1/8 ----
    #pragma unroll
    for (int n = 0; n < 4; ++n){
      const int gc = cbase + n * 16 + lrow;
      #pragma unroll
      for (int i = 0; i < 4; ++i){
        float svv = s[n][i] * 0.125f;
        if (rbase + lkb * 4 + i == gc) svv = 0.f;
        s[n][i] = svv;
      }
    }
    // ---- defer-max (T13): common path has NO cross-lane reduction, NO rescale ----
    float lmax[4];
    #pragma unroll
    for (int i = 0; i < 4; ++i)
      lmax[i] = fmaxf(fmaxf(s[0][i], s[1][i]), fmaxf(s[2][i], s[3][i]));
    const bool ok = (lmax[0] <= m_r[0] + 8.f) && (lmax[1] <= m_r[1] + 8.f) &&
                    (lmax[2] <= m_r[2] + 8.f) && (lmax[3] <= m_r[3] + 8.f);
    if (!__all(ok)){
      // rare path: exact per-row max, rescale running state
      #pragma unroll
      for (int i = 0; i < 4; ++i){
        float tmax = lmax[i];
        #pragma unroll
        for (int d = 1; d < 16; d <<= 1)
          tmax = fmaxf(tmax, __shfl_xor(tmax, d, 64));
        const float mn = fmaxf(m_r[i], tmax);
        const float sc = __expf(m_r[i] - mn);   // exp(-inf)=0 on first trigger
        m_r[i] = mn;
        l_r[i] *= sc;
        #pragma unroll
        for (int fs = 0; fs < 4; ++fs) oacc[fs][i] *= sc;
      }
    }
    // ---- P = exp(s - m); accumulate per-lane l ----
    float pr[4][4];
    #pragma unroll
    for (int i = 0; i < 4; ++i){
      const float mi = m_r[i];
      float ps = 0.f;
      #pragma unroll
      for (int n = 0; n < 4; ++n){
        const float pv = __expf(s[n][i] - mi);
        pr[n][i] = pv;
        ps += pv;
      }
      l_r[i] += ps;                 // no shuffle: reduced once after the loop
    }
    // ---- P: C-layout -> A-layout via wave-private LDS ----
    #pragma unroll
    for (int n = 0; n < 4; ++n){
      #pragma unroll
      for (int i = 0; i < 4; ++i)
        pl[lkb * 4 + i][n * 16 + lrow] = f2bf(pr[n][i]);
    }
    const bf16x8 pa0 = *(const bf16x8*)(&pl[lrow][lkb * 8]);
    const bf16x8 pa1 = *(const bf16x8*)(&pl[lrow][32 + lkb * 8]);
    // ---- O += P V ----
    #pragma unroll
    for (int kc = 0; kc < 2; ++kc){
      const bf16x8 pa = kc ? pa1 : pa0;
      #pragma unroll
      for (int fs = 0; fs < 4; ++fs)
        oacc[fs] = __builtin_amdgcn_mfma_f32_16x16x32_bf16(pa, bvf[kc][fs], oacc[fs], 0, 0, 0);
    }
  }
  // ---- single final l reduction over the 16-lane row group ----
  #pragma unroll
  for (int i = 0; i < 4; ++i){
    #pragma unroll
    for (int d = 1; d < 16; d <<= 1)
      l_r[i] += __shfl_xor(l_r[i], d, 64);
  }
  // ---- store UNNORMALIZED partial O + (m, l) per row ----
  float* Ob = Op + (size_t)(b * split + sp) * N_ * F_;
  #pragma unroll
  for (int i = 0; i < 4; ++i){
    const int row = rbase + lkb * 4 + i;
    #pragma unroll
    for (int fs = 0; fs < 4; ++fs)
      Ob[(size_t)row * F_ + fs * 16 + lrow] = oacc[fs][i];
    if (lrow == 0){
      mp[(size_t)(b * split + sp) * N_ + row] = m_r[i];
      lp[(size_t)(b * split + sp) * N_ + row] = l_r[i];
    }
  }
}

// ---------------- combine partials ----------------
__global__ __launch_bounds__(256) void combine_kernel(
    const float* __restrict__ Op, const float* __restrict__ mp,
    const float* __restrict__ lp, float* __restrict__ o, int split)
{
  const int gid = blockIdx.x * 256 + threadIdx.x;   // over B*N*F
  const int f = gid & 63;
  const int n = (gid >> 6) & (N_ - 1);
  const int b = gid >> 18;
  float gm = -INFINITY;
  for (int s = 0; s < split; ++s)
    gm = fmaxf(gm, mp[(size_t)(b * split + s) * N_ + n]);
  float L = 0.f, O = 0.f;
  for (int s = 0; s < split; ++s){
    const float w = __expf(mp[(size_t)(b * split + s) * N_ + n] - gm);
    L += lp[(size_t)(b * split + s) * N_ + n] * w;
    O += Op[((size_t)(b * split + s) * N_ + n) * F_ + f] * w;
  }
  o[gid] = O / L;
}

// ---------------- final conv: relu(conv(attn_out, Wr) + br) -> d_out fp32 ----------------
__global__ __launch_bounds__(256) void conv_out_kernel(
    const float* __restrict__ xin,
    const float* __restrict__ Wr, const float* __restrict__ br,
    float* __restrict__ out)
{
  const int co = threadIdx.x & 63;
  int p0 = blockIdx.x * 32 + ((threadIdx.x >> 6) << 3);
  p0 = __builtin_amdgcn_readfirstlane(p0);
  const int b  = p0 >> 12;
  const int y  = (p0 >> 6) & 63;
  const int x0 = p0 & 63;

  float acc[8];
  const float bb = br[co];
  #pragma unroll
  for (int p = 0; p < 8; ++p) acc[p] = bb;

  #pragma unroll
  for (int ky = 0; ky < 3; ++ky){
    const int yy = y + ky - 1;
    if (yy < 0 || yy >= H_) continue;
    const float* xrow = xin + (size_t)((b * H_ + yy) * W_) * F_;
    for (int ci = 0; ci < F_; ++ci){
      float xv[10];
      #pragma unroll
      for (int t = 0; t < 10; ++t){
        const int xx = x0 - 1 + t;
        xv[t] = (xx >= 0 && xx < W_) ? xrow[xx * F_ + ci] : 0.f;
      }
      #pragma unroll
      for (int kx = 0; kx < 3; ++kx){
        const float wv_ = Wr[(((ky * 3 + kx) * F_) + ci) * F_ + co];
        #pragma unroll
        for (int p = 0; p < 8; ++p)
          acc[p] = fmaf(xv[p + kx], wv_, acc[p]);
      }
    }
  }
  #pragma unroll
  for (int p = 0; p < 8; ++p)
    out[(size_t)(p0 + p) * F_ + co] = fmaxf(acc[p], 0.f);
}

extern "C" void kernel_launch(void* const* d_in, const int* in_sizes, int n_in,
                              void* d_out, int out_size, void* d_ws, size_t ws_size,
                              hipStream_t stream)
{
  const float* x  = (const float*)d_in[0];
  const float* Wk = (const float*)d_in[1];
  const float* bk = (const float*)d_in[2];
  const float* Wq = (const float*)d_in[3];
  const float* bq = (const float*)d_in[4];
  const float* Wv = (const float*)d_in[5];
  const float* bv = (const float*)d_in[6];
  const float* Wr = (const float*)d_in[7];
  const float* br = (const float*)d_in[8];
  float* out = (float*)d_out;

  const size_t BNF = (size_t)B_ * N_ * F_;
  const size_t fixed_bytes = BNF * 2 * 3 + BNF * 4;
  int split = 8;
  while (split > 1 &&
         fixed_bytes + (size_t)split * (BNF * 4 + 2 * (size_t)B_ * N_ * 4) > ws_size)
    split >>= 1;

  short* qw = (short*)d_ws;
  short* kw = qw + BNF;
  short* vt = kw + BNF;
  float* attn = (float*)(vt + BNF);
  float* Op = attn + BNF;
  float* mp = Op + (size_t)split * BNF;
  float* lp = mp + (size_t)split * B_ * N_;

  hipLaunchKernelGGL(conv_qkv_kernel, dim3(1024), dim3(256), 0, stream,
                     x, Wk, bk, Wq, bq, Wv, bv, qw, kw, vt);
  hipLaunchKernelGGL(attn_kernel, dim3(B_ * 64 * split), dim3(256), 0, stream,
                     qw, kw, vt, Op, mp, lp, split);
  hipLaunchKernelGGL(combine_kernel, dim3((B_ * N_ * F_) / 256), dim3(256), 0, stream,
                     Op, mp, lp, attn, split);
  hipLaunchKernelGGL(conv_out_kernel, dim3(512), dim3(256), 0, stream,
                     attn, Wr, br, out);
}

// Round 8
// 120.849 us; speedup vs baseline: 2.7824x; 2.5635x over previous
//
#include <hip/hip_runtime.h>
#include <hip/hip_bf16.h>
#include <math.h>

#define B_ 4
#define H_ 64
#define W_ 64
#define C_ 64
#define F_ 64
#define N_ 4096

typedef __attribute__((ext_vector_type(8))) short bf16x8;
typedef __attribute__((ext_vector_type(4))) short bf16x4;
typedef __attribute__((ext_vector_type(4))) float f32x4;

static __device__ __forceinline__ short f2bf(float f){
  union { __hip_bfloat16 h; short s; } u;
  u.h = __float2bfloat16(f);
  return u.s;
}

// ---------------- prep: x fp32 -> bf16 ----------------
__global__ __launch_bounds__(256) void prep_x_kernel(
    const float* __restrict__ x, short* __restrict__ xb)
{
  const int i4 = blockIdx.x * 256 + threadIdx.x;   // over B*N*C/4
  const float4 v = ((const float4*)x)[i4];
  bf16x4 o;
  o[0] = f2bf(v.x); o[1] = f2bf(v.y); o[2] = f2bf(v.z); o[3] = f2bf(v.w);
  ((bf16x4*)xb)[i4] = o;
}

// ---------------- prep: weights HWIO fp32 -> Wt[256][576] bf16 (rows: 0-63 k, 64-127 q, 128-191 v, 192-255 out) ----
__global__ __launch_bounds__(256) void prep_w_kernel(
    const float* __restrict__ Wk, const float* __restrict__ Wq,
    const float* __restrict__ Wv, const float* __restrict__ Wr,
    short* __restrict__ Wt)
{
  const int gid = blockIdx.x * 256 + threadIdx.x;  // 256*576
  const int oc = gid / 576;
  const int kk = gid % 576;                        // (ky*3+kx)*64 + ci
  const int srcofs = (kk >> 6) * 4096 + (kk & 63) * 64 + (oc & 63);
  const float* src = (oc < 64) ? Wk : (oc < 128) ? Wq : (oc < 192) ? Wv : Wr;
  Wt[gid] = f2bf(src[srcofs]);
}

// ---------------- conv QKV as implicit-GEMM MFMA: 16 px/block, 192 outs, K=576 ----------------
__global__ __launch_bounds__(256) void conv_qkv_mfma(
    const short* __restrict__ xb, const short* __restrict__ Wt,
    const float* __restrict__ bk, const float* __restrict__ bq,
    const float* __restrict__ bv,
    short* __restrict__ qo, short* __restrict__ ko, short* __restrict__ vt)
{
  const int lane = threadIdx.x & 63;
  const int w    = threadIdx.x >> 6;     // wave -> out-channel slice w*16..w*16+15 of each conv
  const int lrow = lane & 15;
  const int lkb  = lane >> 4;
  const int p0   = blockIdx.x << 4;      // 16 consecutive pixels (same image row)
  const int b    = p0 >> 12;
  const int y    = (p0 >> 6) & 63;
  const int xx0  = (p0 & 63) + lrow;     // this lane's pixel x (A-row = lrow)

  f32x4 ak, aq, av;
  #pragma unroll
  for (int i = 0; i < 4; ++i){ ak[i] = 0.f; aq[i] = 0.f; av[i] = 0.f; }

  const short* wr_k = Wt + (      w * 16 + lrow) * 576;
  const short* wr_q = Wt + ( 64 + w * 16 + lrow) * 576;
  const short* wr_v = Wt + (128 + w * 16 + lrow) * 576;

  #pragma unroll
  for (int ks = 0; ks < 18; ++ks){
    const int kxy = ks >> 1;
    const int ky  = kxy / 3;
    const int kx  = kxy - ky * 3;
    const int ci0 = (ks & 1) << 5;
    const int yy  = y + ky - 1;
    const int xx  = xx0 + kx - 1;
    bf16x8 a = {0,0,0,0,0,0,0,0};
    if ((unsigned)yy < 64u && (unsigned)xx < 64u)
      a = *(const bf16x8*)(xb + ((((b << 6) + yy) << 6) + xx) * 64 + ci0 + lkb * 8);
    const bf16x8 wk8 = *(const bf16x8*)(wr_k + ks * 32 + lkb * 8);
    const bf16x8 wq8 = *(const bf16x8*)(wr_q + ks * 32 + lkb * 8);
    const bf16x8 wv8 = *(const bf16x8*)(wr_v + ks * 32 + lkb * 8);
    ak = __builtin_amdgcn_mfma_f32_16x16x32_bf16(a, wk8, ak, 0, 0, 0);
    aq = __builtin_amdgcn_mfma_f32_16x16x32_bf16(a, wq8, aq, 0, 0, 0);
    av = __builtin_amdgcn_mfma_f32_16x16x32_bf16(a, wv8, av, 0, 0, 0);
  }
  // C layout: col=lane&15 -> out channel, row=(lane>>4)*4+i -> pixel
  const int oc = w * 16 + lrow;
  const float bkv = bk[oc], bqv = bq[oc], bvv = bv[oc];
  bf16x4 vp;
  #pragma unroll
  for (int i = 0; i < 4; ++i){
    const int p = p0 + (lkb << 2) + i;
    const float kvv = ak[i] + bkv;
    ko[p * 64 + oc] = f2bf(kvv > 0.f ? kvv : expm1f(kvv));   // elu
    const float qvv = aq[i] + bqv;
    qo[p * 64 + oc] = f2bf(qvv > 0.f ? qvv : expm1f(qvv));   // elu
    const float vvv = av[i] + bvv;
    vp[i] = f2bf(vvv > 0.f ? vvv : 0.f);                     // relu
  }
  // v transposed: vt[b][oc][pixel], 4 consecutive pixels -> 8B store
  *(bf16x4*)(vt + ((size_t)(b * 64 + oc)) * 4096 + (p0 & 4095) + (lkb << 2)) = vp;
}

// ---------------- flash attention (column-split, LDS-staged K/V, defer-max, lazy l) ----------------
__global__ __launch_bounds__(256, 3) void attn_kernel(
    const short* __restrict__ q, const short* __restrict__ k,
    const short* __restrict__ vt, float* __restrict__ Op,
    float* __restrict__ mp, float* __restrict__ lp, int split)
{
  const int tid  = threadIdx.x;
  const int lane = tid & 63;
  const int wv   = tid >> 6;
  const int lrow = lane & 15;
  const int lkb  = lane >> 4;

  const int bid  = blockIdx.x;
  const int b    = bid / (64 * split);
  const int rem  = bid % (64 * split);
  const int rt   = rem / split;
  const int sp   = rem % split;
  const int rbase = (rt << 6) + (wv << 4);
  const int tiles = (N_ / 64) / split;
  const int ct0   = sp * tiles;

  const short* qb = q  + (size_t)b * N_ * F_;
  const short* kb = k  + (size_t)b * N_ * F_;
  const short* vb = vt + (size_t)b * F_ * N_;

  const bf16x8 aq0 = *(const bf16x8*)(qb + (rbase + lrow) * F_ + lkb * 8);
  const bf16x8 aq1 = *(const bf16x8*)(qb + (rbase + lrow) * F_ + 32 + lkb * 8);

  __shared__ short kbuf[2][64 * 64];
  __shared__ short vbuf[2][64 * 64];
  __shared__ short p_lds[4][16][72];   // 72: row-stride 144B -> 2-way max on write & read
  short (*pl)[72] = p_lds[wv];         // wave-private

  // staging: each thread stages 2 rows of K and 2 rows of V (16B each)
  const int srow = tid >> 3;           // 0..31
  const int sc16 = tid & 7;            // 16B granule
  const int dst0 = (srow * 128)        + ((sc16 * 16) ^ ((srow & 7) << 4));
  const int dst1 = ((srow + 32) * 128) + ((sc16 * 16) ^ ((srow & 7) << 4));

  float m_r[4], l_r[4];
  f32x4 oacc[4];
  #pragma unroll
  for (int i = 0; i < 4; ++i){ m_r[i] = -INFINITY; l_r[i] = 0.f; }
  #pragma unroll
  for (int fs = 0; fs < 4; ++fs){
    #pragma unroll
    for (int i = 0; i < 4; ++i) oacc[fs][i] = 0.f;
  }

  // ---- stage tile 0 ----
  int cbase = ct0 << 6;
  bf16x8 sk0 = *(const bf16x8*)(kb + (cbase + srow) * 64      + sc16 * 8);
  bf16x8 sk1 = *(const bf16x8*)(kb + (cbase + srow + 32) * 64 + sc16 * 8);
  bf16x8 sv0 = *(const bf16x8*)(vb + (size_t)srow * N_        + cbase + sc16 * 8);
  bf16x8 sv1 = *(const bf16x8*)(vb + (size_t)(srow + 32) * N_ + cbase + sc16 * 8);
  *(bf16x8*)((char*)kbuf[0] + dst0) = sk0;
  *(bf16x8*)((char*)kbuf[0] + dst1) = sk1;
  *(bf16x8*)((char*)vbuf[0] + dst0) = sv0;
  *(bf16x8*)((char*)vbuf[0] + dst1) = sv1;
  __syncthreads();

  int cur = 0;
  for (int t = 0; t < tiles; ++t){
    cbase = (ct0 + t) << 6;
    // ---- issue next-tile global loads early (latency hides under compute) ----
    if (t + 1 < tiles){
      const int cb2 = (ct0 + t + 1) << 6;
      sk0 = *(const bf16x8*)(kb + (cb2 + srow) * 64      + sc16 * 8);
      sk1 = *(const bf16x8*)(kb + (cb2 + srow + 32) * 64 + sc16 * 8);
      sv0 = *(const bf16x8*)(vb + (size_t)srow * N_        + cb2 + sc16 * 8);
      sv1 = *(const bf16x8*)(vb + (size_t)(srow + 32) * N_ + cb2 + sc16 * 8);
    }
    const char* kc = (const char*)kbuf[cur];
    const char* vc = (const char*)vbuf[cur];
    // ---- S = Q K^T (K frags from LDS, swizzled) ----
    f32x4 s[4];
    #pragma unroll
    for (int n = 0; n < 4; ++n){
      #pragma unroll
      for (int i = 0; i < 4; ++i) s[n][i] = 0.f;
    }
    #pragma unroll
    for (int n = 0; n < 4; ++n){
      const int r   = n * 16 + lrow;
      const int swz = (r & 7) << 4;
      const bf16x8 b0 = *(const bf16x8*)(kc + r * 128 + ((lkb * 16) ^ swz));
      const bf16x8 b1 = *(const bf16x8*)(kc + r * 128 + ((64 + lkb * 16) ^ swz));
      s[n] = __builtin_amdgcn_mfma_f32_16x16x32_bf16(aq0, b0, s[n], 0, 0, 0);
      s[n] = __builtin_amdgcn_mfma_f32_16x16x32_bf16(aq1, b1, s[n], 0, 0, 0);
    }
    // ---- V frags from LDS ----
    bf16x8 bvf[2][4];
    #pragma unroll
    for (int kc2 = 0; kc2 < 2; ++kc2){
      #pragma unroll
      for (int fs = 0; fs < 4; ++fs){
        const int r   = fs * 16 + lrow;
        const int swz = (r & 7) << 4;
        bvf[kc2][fs] = *(const bf16x8*)(vc + r * 128 + ((kc2 * 64 + lkb * 16) ^ swz));
      }
    }
    // ---- mask diagonal to 0 (NOT -inf), scale 1/8 ----
    #pragma unroll
    for (int n = 0; n < 4; ++n){
      const int gc = cbase + n * 16 + lrow;
      #pragma unroll
      for (int i = 0; i < 4; ++i){
        float svv = s[n][i] * 0.125f;
        if (rbase + lkb * 4 + i == gc) svv = 0.f;
        s[n][i] = svv;
      }
    }
    // ---- defer-max: common path has no cross-lane reduce, no rescale ----
    float lmax[4];
    #pragma unroll
    for (int i = 0; i < 4; ++i)
      lmax[i] = fmaxf(fmaxf(s[0][i], s[1][i]), fmaxf(s[2][i], s[3][i]));
    const bool ok = (lmax[0] <= m_r[0] + 8.f) && (lmax[1] <= m_r[1] + 8.f) &&
                    (lmax[2] <= m_r[2] + 8.f) && (lmax[3] <= m_r[3] + 8.f);
    if (!__all(ok)){
      #pragma unroll
      for (int i = 0; i < 4; ++i){
        float tmax = lmax[i];
        #pragma unroll
        for (int d = 1; d < 16; d <<= 1)
          tmax = fmaxf(tmax, __shfl_xor(tmax, d, 64));
        const float mn = fmaxf(m_r[i], tmax);
        const float sc = __expf(m_r[i] - mn);
        m_r[i] = mn;
        l_r[i] *= sc;
        #pragma unroll
        for (int fs = 0; fs < 4; ++fs) oacc[fs][i] *= sc;
      }
    }
    // ---- P = exp(s - m), per-lane l accumulation ----
    float pr[4][4];
    #pragma unroll
    for (int i = 0; i < 4; ++i){
      const float mi = m_r[i];
      float ps = 0.f;
      #pragma unroll
      for (int n = 0; n < 4; ++n){
        const float pv = __expf(s[n][i] - mi);
        pr[n][i] = pv;
        ps += pv;
      }
      l_r[i] += ps;
    }
    // ---- P: C-layout -> A-layout via wave-private LDS ----
    #pragma unroll
    for (int n = 0; n < 4; ++n){
      #pragma unroll
      for (int i = 0; i < 4; ++i)
        pl[lkb * 4 + i][n * 16 + lrow] = f2bf(pr[n][i]);
    }
    const bf16x8 pa0 = *(const bf16x8*)(&pl[lrow][lkb * 8]);
    const bf16x8 pa1 = *(const bf16x8*)(&pl[lrow][32 + lkb * 8]);
    // ---- O += P V ----
    #pragma unroll
    for (int kc2 = 0; kc2 < 2; ++kc2){
      const bf16x8 pa = kc2 ? pa1 : pa0;
      #pragma unroll
      for (int fs = 0; fs < 4; ++fs)
        oacc[fs] = __builtin_amdgcn_mfma_f32_16x16x32_bf16(pa, bvf[kc2][fs], oacc[fs], 0, 0, 0);
    }
    // ---- double-buffer handoff ----
    __syncthreads();
    if (t + 1 < tiles){
      const int nxt = cur ^ 1;
      *(bf16x8*)((char*)kbuf[nxt] + dst0) = sk0;
      *(bf16x8*)((char*)kbuf[nxt] + dst1) = sk1;
      *(bf16x8*)((char*)vbuf[nxt] + dst0) = sv0;
      *(bf16x8*)((char*)vbuf[nxt] + dst1) = sv1;
    }
    __syncthreads();
    cur ^= 1;
  }
  // ---- single final l reduction ----
  #pragma unroll
  for (int i = 0; i < 4; ++i){
    #pragma unroll
    for (int d = 1; d < 16; d <<= 1)
      l_r[i] += __shfl_xor(l_r[i], d, 64);
  }
  float* Ob = Op + (size_t)(b * split + sp) * N_ * F_;
  #pragma unroll
  for (int i = 0; i < 4; ++i){
    const int row = rbase + lkb * 4 + i;
    #pragma unroll
    for (int fs = 0; fs < 4; ++fs)
      Ob[(size_t)row * F_ + fs * 16 + lrow] = oacc[fs][i];
    if (lrow == 0){
      mp[(size_t)(b * split + sp) * N_ + row] = m_r[i];
      lp[(size_t)(b * split + sp) * N_ + row] = l_r[i];
    }
  }
}

// ---------------- combine partials -> bf16 attn output ----------------
__global__ __launch_bounds__(256) void combine_kernel(
    const float* __restrict__ Op, const float* __restrict__ mp,
    const float* __restrict__ lp, short* __restrict__ ob, int split)
{
  const int gid = blockIdx.x * 256 + threadIdx.x;
  const int f = gid & 63;
  const int n = (gid >> 6) & (N_ - 1);
  const int b = gid >> 18;
  float gm = -INFINITY;
  for (int s = 0; s < split; ++s)
    gm = fmaxf(gm, mp[(size_t)(b * split + s) * N_ + n]);
  float L = 0.f, O = 0.f;
  for (int s = 0; s < split; ++s){
    const float w = __expf(mp[(size_t)(b * split + s) * N_ + n] - gm);
    L += lp[(size_t)(b * split + s) * N_ + n] * w;
    O += Op[((size_t)(b * split + s) * N_ + n) * F_ + f] * w;
  }
  ob[gid] = f2bf(O / L);
}

// ---------------- final conv as implicit-GEMM MFMA: relu(conv(attn, Wr) + br) -> fp32 ----------------
__global__ __launch_bounds__(256) void conv_out_mfma(
    const short* __restrict__ ab, const short* __restrict__ Wt,
    const float* __restrict__ br, float* __restrict__ out)
{
  const int lane = threadIdx.x & 63;
  const int w    = threadIdx.x >> 6;
  const int lrow = lane & 15;
  const int lkb  = lane >> 4;
  const int p0   = blockIdx.x << 4;
  const int b    = p0 >> 12;
  const int y    = (p0 >> 6) & 63;
  const int xx0  = (p0 & 63) + lrow;

  f32x4 acc;
  #pragma unroll
  for (int i = 0; i < 4; ++i) acc[i] = 0.f;
  const short* wr = Wt + (192 + w * 16 + lrow) * 576;

  #pragma unroll
  for (int ks = 0; ks < 18; ++ks){
    const int kxy = ks >> 1;
    const int ky  = kxy / 3;
    const int kx  = kxy - ky * 3;
    const int ci0 = (ks & 1) << 5;
    const int yy  = y + ky - 1;
    const int xx  = xx0 + kx - 1;
    bf16x8 a = {0,0,0,0,0,0,0,0};
    if ((unsigned)yy < 64u && (unsigned)xx < 64u)
      a = *(const bf16x8*)(ab + ((((b << 6) + yy) << 6) + xx) * 64 + ci0 + lkb * 8);
    const bf16x8 w8 = *(const bf16x8*)(wr + ks * 32 + lkb * 8);
    acc = __builtin_amdgcn_mfma_f32_16x16x32_bf16(a, w8, acc, 0, 0, 0);
  }
  const int oc = w * 16 + lrow;
  const float bb = br[oc];
  #pragma unroll
  for (int i = 0; i < 4; ++i){
    const int p = p0 + (lkb << 2) + i;
    out[(size_t)p * 64 + oc] = fmaxf(acc[i] + bb, 0.f);
  }
}

extern "C" void kernel_launch(void* const* d_in, const int* in_sizes, int n_in,
                              void* d_out, int out_size, void* d_ws, size_t ws_size,
                              hipStream_t stream)
{
  const float* x  = (const float*)d_in[0];
  const float* Wk = (const float*)d_in[1];
  const float* bk = (const float*)d_in[2];
  const float* Wq = (const float*)d_in[3];
  const float* bq = (const float*)d_in[4];
  const float* Wv = (const float*)d_in[5];
  const float* bv = (const float*)d_in[6];
  const float* Wr = (const float*)d_in[7];
  const float* br = (const float*)d_in[8];
  float* out = (float*)d_out;

  const size_t BNF = (size_t)B_ * N_ * F_;          // 1,048,576
  // fixed: xb16 + Wt(256*576) + q + k + vt + attnb  (bf16)
  const size_t fixed_shorts = BNF * 5 + 256 * 576;
  const size_t fixed_bytes  = fixed_shorts * 2;
  int split = 8;
  while (split > 1 &&
         fixed_bytes + (size_t)split * (BNF * 4 + 2 * (size_t)B_ * N_ * 4) > ws_size)
    split >>= 1;

  short* xb16 = (short*)d_ws;
  short* Wt   = xb16 + BNF;
  short* qw   = Wt + 256 * 576;
  short* kw   = qw + BNF;
  short* vt   = kw + BNF;
  short* attnb= vt + BNF;
  float* Op   = (float*)(attnb + BNF);
  float* mp   = Op + (size_t)split * BNF;
  float* lp   = mp + (size_t)split * B_ * N_;

  hipLaunchKernelGGL(prep_x_kernel, dim3(1024), dim3(256), 0, stream, x, xb16);
  hipLaunchKernelGGL(prep_w_kernel, dim3(576), dim3(256), 0, stream, Wk, Wq, Wv, Wr, Wt);
  hipLaunchKernelGGL(conv_qkv_mfma, dim3(1024), dim3(256), 0, stream,
                     xb16, Wt, bk, bq, bv, qw, kw, vt);
  hipLaunchKernelGGL(attn_kernel, dim3(B_ * 64 * split), dim3(256), 0, stream,
                     qw, kw, vt, Op, mp, lp, split);
  hipLaunchKernelGGL(combine_kernel, dim3((B_ * N_ * F_) / 256), dim3(256), 0, stream,
                     Op, mp, lp, attnb, split);
  hipLaunchKernelGGL(conv_out_mfma, dim3(1024), dim3(256), 0, stream,
                     attnb, Wt, br, out);
}

// Round 9
// 112.996 us; speedup vs baseline: 2.9758x; 1.0695x over previous
//
#include <hip/hip_runtime.h>
#include <hip/hip_bf16.h>
#include <math.h>

#define B_ 4
#define H_ 64
#define W_ 64
#define C_ 64
#define F_ 64
#define N_ 4096

typedef __attribute__((ext_vector_type(8))) short bf16x8;
typedef __attribute__((ext_vector_type(4))) short bf16x4;
typedef __attribute__((ext_vector_type(4))) float f32x4;

static __device__ __forceinline__ short f2bf(float f){
  union { __hip_bfloat16 h; short s; } u;
  u.h = __float2bfloat16(f);
  return u.s;
}

// ---------------- prep: x fp32 -> bf16 ----------------
__global__ __launch_bounds__(256) void prep_x_kernel(
    const float* __restrict__ x, short* __restrict__ xb)
{
  const int i4 = blockIdx.x * 256 + threadIdx.x;   // over B*N*C/4
  const float4 v = ((const float4*)x)[i4];
  bf16x4 o;
  o[0] = f2bf(v.x); o[1] = f2bf(v.y); o[2] = f2bf(v.z); o[3] = f2bf(v.w);
  ((bf16x4*)xb)[i4] = o;
}

// ---------------- prep: weights HWIO fp32 -> Wt[256][576] bf16 ----------------
__global__ __launch_bounds__(256) void prep_w_kernel(
    const float* __restrict__ Wk, const float* __restrict__ Wq,
    const float* __restrict__ Wv, const float* __restrict__ Wr,
    short* __restrict__ Wt)
{
  const int gid = blockIdx.x * 256 + threadIdx.x;  // 256*576
  const int oc = gid / 576;
  const int kk = gid % 576;                        // (ky*3+kx)*64 + ci
  const int srcofs = (kk >> 6) * 4096 + (kk & 63) * 64 + (oc & 63);
  const float* src = (oc < 64) ? Wk : (oc < 128) ? Wq : (oc < 192) ? Wv : Wr;
  Wt[gid] = f2bf(src[srcofs]);
}

// ---------------- conv QKV as implicit-GEMM MFMA (q pre-scaled by 1/8) ----------------
__global__ __launch_bounds__(256) void conv_qkv_mfma(
    const short* __restrict__ xb, const short* __restrict__ Wt,
    const float* __restrict__ bk, const float* __restrict__ bq,
    const float* __restrict__ bv,
    short* __restrict__ qo, short* __restrict__ ko, short* __restrict__ vt)
{
  const int lane = threadIdx.x & 63;
  const int w    = threadIdx.x >> 6;
  const int lrow = lane & 15;
  const int lkb  = lane >> 4;
  const int p0   = blockIdx.x << 4;
  const int b    = p0 >> 12;
  const int y    = (p0 >> 6) & 63;
  const int xx0  = (p0 & 63) + lrow;

  f32x4 ak, aq, av;
  #pragma unroll
  for (int i = 0; i < 4; ++i){ ak[i] = 0.f; aq[i] = 0.f; av[i] = 0.f; }

  const short* wr_k = Wt + (      w * 16 + lrow) * 576;
  const short* wr_q = Wt + ( 64 + w * 16 + lrow) * 576;
  const short* wr_v = Wt + (128 + w * 16 + lrow) * 576;

  #pragma unroll
  for (int ks = 0; ks < 18; ++ks){
    const int kxy = ks >> 1;
    const int ky  = kxy / 3;
    const int kx  = kxy - ky * 3;
    const int ci0 = (ks & 1) << 5;
    const int yy  = y + ky - 1;
    const int xx  = xx0 + kx - 1;
    bf16x8 a = {0,0,0,0,0,0,0,0};
    if ((unsigned)yy < 64u && (unsigned)xx < 64u)
      a = *(const bf16x8*)(xb + ((((b << 6) + yy) << 6) + xx) * 64 + ci0 + lkb * 8);
    const bf16x8 wk8 = *(const bf16x8*)(wr_k + ks * 32 + lkb * 8);
    const bf16x8 wq8 = *(const bf16x8*)(wr_q + ks * 32 + lkb * 8);
    const bf16x8 wv8 = *(const bf16x8*)(wr_v + ks * 32 + lkb * 8);
    ak = __builtin_amdgcn_mfma_f32_16x16x32_bf16(a, wk8, ak, 0, 0, 0);
    aq = __builtin_amdgcn_mfma_f32_16x16x32_bf16(a, wq8, aq, 0, 0, 0);
    av = __builtin_amdgcn_mfma_f32_16x16x32_bf16(a, wv8, av, 0, 0, 0);
  }
  const int oc = w * 16 + lrow;
  const float bkv = bk[oc], bqv = bq[oc], bvv = bv[oc];
  bf16x4 vp;
  #pragma unroll
  for (int i = 0; i < 4; ++i){
    const int p = p0 + (lkb << 2) + i;
    const float kvv = ak[i] + bkv;
    ko[p * 64 + oc] = f2bf(kvv > 0.f ? kvv : expm1f(kvv));            // elu
    const float qvv = aq[i] + bqv;
    const float qe  = (qvv > 0.f ? qvv : expm1f(qvv)) * 0.125f;       // elu * 1/sqrt(F): exact in bf16
    qo[p * 64 + oc] = f2bf(qe);
    const float vvv = av[i] + bvv;
    vp[i] = f2bf(vvv > 0.f ? vvv : 0.f);                              // relu
  }
  *(bf16x4*)(vt + ((size_t)(b * 64 + oc)) * 4096 + (p0 & 4095) + (lkb << 2)) = vp;
}

// ---------------- flash attention: 32 rows/wave, constant-m softmax, LDS-staged K/V ----------------
// m == 16 fixed: exp(s-16) can't overflow (would need s>104); diag forced to s=0 pre-exp;
// partials exact up to global scale e^-16 which cancels in O/L. No max tracking at all.
__global__ __launch_bounds__(256, 3) void attn_kernel(
    const short* __restrict__ q, const short* __restrict__ k,
    const short* __restrict__ vt, float* __restrict__ Op,
    float* __restrict__ lp, int split)
{
  const int tid  = threadIdx.x;
  const int lane = tid & 63;
  const int wv   = tid >> 6;
  const int lrow = lane & 15;
  const int lkb  = lane >> 4;

  const int bid  = blockIdx.x;
  const int b    = bid / (32 * split);
  const int rem  = bid % (32 * split);
  const int rt   = rem / split;              // 128-row tile
  const int sp   = rem % split;
  const int rbase = (rt << 7) + (wv << 5);   // this wave's 32 rows
  const int tiles = (N_ / 64) / split;
  const int ct0   = sp * tiles;

  const short* qb = q  + (size_t)b * N_ * F_;
  const short* kb = k  + (size_t)b * N_ * F_;
  const short* vb = vt + (size_t)b * F_ * N_;

  // Q fragments for both 16-row groups (pre-scaled by 1/8 at conv time)
  const bf16x8 aq00 = *(const bf16x8*)(qb + (rbase +      lrow) * F_ + lkb * 8);
  const bf16x8 aq01 = *(const bf16x8*)(qb + (rbase +      lrow) * F_ + 32 + lkb * 8);
  const bf16x8 aq10 = *(const bf16x8*)(qb + (rbase + 16 + lrow) * F_ + lkb * 8);
  const bf16x8 aq11 = *(const bf16x8*)(qb + (rbase + 16 + lrow) * F_ + 32 + lkb * 8);

  __shared__ short kbuf[2][64 * 64];
  __shared__ short vbuf[2][64 * 64];
  __shared__ short p_lds[4][2][16][72];      // [wave][rowgroup][16][72]: 144B rows, 16B aligned

  const int srow = tid >> 3;
  const int sc16 = tid & 7;
  const int dst0 = (srow * 128)        + ((sc16 * 16) ^ ((srow & 7) << 4));
  const int dst1 = ((srow + 32) * 128) + ((sc16 * 16) ^ ((srow & 7) << 4));

  float l_r[2][4];
  f32x4 oacc[2][4];
  #pragma unroll
  for (int g = 0; g < 2; ++g){
    #pragma unroll
    for (int i = 0; i < 4; ++i) l_r[g][i] = 0.f;
    #pragma unroll
    for (int fs = 0; fs < 4; ++fs)
      #pragma unroll
      for (int i = 0; i < 4; ++i) oacc[g][fs][i] = 0.f;
  }

  // ---- stage tile 0 ----
  int cbase = ct0 << 6;
  bf16x8 sk0 = *(const bf16x8*)(kb + (cbase + srow) * 64      + sc16 * 8);
  bf16x8 sk1 = *(const bf16x8*)(kb + (cbase + srow + 32) * 64 + sc16 * 8);
  bf16x8 sv0 = *(const bf16x8*)(vb + (size_t)srow * N_        + cbase + sc16 * 8);
  bf16x8 sv1 = *(const bf16x8*)(vb + (size_t)(srow + 32) * N_ + cbase + sc16 * 8);
  *(bf16x8*)((char*)kbuf[0] + dst0) = sk0;
  *(bf16x8*)((char*)kbuf[0] + dst1) = sk1;
  *(bf16x8*)((char*)vbuf[0] + dst0) = sv0;
  *(bf16x8*)((char*)vbuf[0] + dst1) = sv1;
  __syncthreads();

  int cur = 0;
  for (int t = 0; t < tiles; ++t){
    cbase = (ct0 + t) << 6;
    if (t + 1 < tiles){
      const int cb2 = (ct0 + t + 1) << 6;
      sk0 = *(const bf16x8*)(kb + (cb2 + srow) * 64      + sc16 * 8);
      sk1 = *(const bf16x8*)(kb + (cb2 + srow + 32) * 64 + sc16 * 8);
      sv0 = *(const bf16x8*)(vb + (size_t)srow * N_        + cb2 + sc16 * 8);
      sv1 = *(const bf16x8*)(vb + (size_t)(srow + 32) * N_ + cb2 + sc16 * 8);
    }
    const char* kc = (const char*)kbuf[cur];
    const char* vc = (const char*)vbuf[cur];
    // ---- S = Q K^T for both row groups; K frags shared in-register ----
    f32x4 s0[4], s1[4];
    #pragma unroll
    for (int n = 0; n < 4; ++n){
      #pragma unroll
      for (int i = 0; i < 4; ++i){ s0[n][i] = 0.f; s1[n][i] = 0.f; }
    }
    #pragma unroll
    for (int n = 0; n < 4; ++n){
      const int r   = n * 16 + lrow;
      const int swz = (r & 7) << 4;
      const bf16x8 b0 = *(const bf16x8*)(kc + r * 128 + ((lkb * 16) ^ swz));
      const bf16x8 b1 = *(const bf16x8*)(kc + r * 128 + ((64 + lkb * 16) ^ swz));
      s0[n] = __builtin_amdgcn_mfma_f32_16x16x32_bf16(aq00, b0, s0[n], 0, 0, 0);
      s0[n] = __builtin_amdgcn_mfma_f32_16x16x32_bf16(aq01, b1, s0[n], 0, 0, 0);
      s1[n] = __builtin_amdgcn_mfma_f32_16x16x32_bf16(aq10, b0, s1[n], 0, 0, 0);
      s1[n] = __builtin_amdgcn_mfma_f32_16x16x32_bf16(aq11, b1, s1[n], 0, 0, 0);
    }
    // ---- softmax numerator: p = exp2(s*log2e - 16*log2e); diag -> s=0 ----
    #pragma unroll
    for (int g = 0; g < 2; ++g){
      f32x4* s = g ? s1 : s0;
      const int rb = rbase + g * 16 + lkb * 4;
      #pragma unroll
      for (int n = 0; n < 4; ++n){
        const int gc = cbase + n * 16 + lrow;
        #pragma unroll
        for (int i = 0; i < 4; ++i){
          float sv = s[n][i];
          if (rb + i == gc) sv = 0.f;
          const float p = exp2f(fmaf(sv, 1.44269504f, -23.0831206f));
          l_r[g][i] += p;
          p_lds[wv][g][lkb * 4 + i][n * 16 + lrow] = f2bf(p);
        }
      }
    }
    // ---- O += P V (V frags shared across row groups) ----
    #pragma unroll
    for (int kc2 = 0; kc2 < 2; ++kc2){
      const bf16x8 pa0 = *(const bf16x8*)(&p_lds[wv][0][lrow][kc2 * 32 + lkb * 8]);
      const bf16x8 pa1 = *(const bf16x8*)(&p_lds[wv][1][lrow][kc2 * 32 + lkb * 8]);
      #pragma unroll
      for (int fs = 0; fs < 4; ++fs){
        const int r   = fs * 16 + lrow;
        const int swz = (r & 7) << 4;
        const bf16x8 bvf = *(const bf16x8*)(vc + r * 128 + ((kc2 * 64 + lkb * 16) ^ swz));
        oacc[0][fs] = __builtin_amdgcn_mfma_f32_16x16x32_bf16(pa0, bvf, oacc[0][fs], 0, 0, 0);
        oacc[1][fs] = __builtin_amdgcn_mfma_f32_16x16x32_bf16(pa1, bvf, oacc[1][fs], 0, 0, 0);
      }
    }
    // ---- double-buffer handoff ----
    __syncthreads();
    if (t + 1 < tiles){
      const int nxt = cur ^ 1;
      *(bf16x8*)((char*)kbuf[nxt] + dst0) = sk0;
      *(bf16x8*)((char*)kbuf[nxt] + dst1) = sk1;
      *(bf16x8*)((char*)vbuf[nxt] + dst0) = sv0;
      *(bf16x8*)((char*)vbuf[nxt] + dst1) = sv1;
    }
    __syncthreads();
    cur ^= 1;
  }
  // ---- final l reduction (once) + store partials ----
  float* Ob = Op + (size_t)(b * split + sp) * N_ * F_;
  #pragma unroll
  for (int g = 0; g < 2; ++g){
    #pragma unroll
    for (int i = 0; i < 4; ++i){
      #pragma unroll
      for (int d = 1; d < 16; d <<= 1)
        l_r[g][i] += __shfl_xor(l_r[g][i], d, 64);
      const int row = rbase + g * 16 + lkb * 4 + i;
      #pragma unroll
      for (int fs = 0; fs < 4; ++fs)
        Ob[(size_t)row * F_ + fs * 16 + lrow] = oacc[g][fs][i];
      if (lrow == 0)
        lp[(size_t)(b * split + sp) * N_ + row] = l_r[g][i];
    }
  }
}

// ---------------- combine partials (constant m: no max pass) -> bf16 ----------------
__global__ __launch_bounds__(256) void combine_kernel(
    const float* __restrict__ Op, const float* __restrict__ lp,
    short* __restrict__ ob, int split)
{
  const int gid = blockIdx.x * 256 + threadIdx.x;
  const int f = gid & 63;
  const int n = (gid >> 6) & (N_ - 1);
  const int b = gid >> 18;
  float L = 0.f, O = 0.f;
  for (int s = 0; s < split; ++s){
    L += lp[(size_t)(b * split + s) * N_ + n];
    O += Op[((size_t)(b * split + s) * N_ + n) * F_ + f];
  }
  ob[gid] = f2bf(O / L);
}

// ---------------- final conv as implicit-GEMM MFMA ----------------
__global__ __launch_bounds__(256) void conv_out_mfma(
    const short* __restrict__ ab, const short* __restrict__ Wt,
    const float* __restrict__ br, float* __restrict__ out)
{
  const int lane = threadIdx.x & 63;
  const int w    = threadIdx.x >> 6;
  const int lrow = lane & 15;
  const int lkb  = lane >> 4;
  const int p0   = blockIdx.x << 4;
  const int b    = p0 >> 12;
  const int y    = (p0 >> 6) & 63;
  const int xx0  = (p0 & 63) + lrow;

  f32x4 acc;
  #pragma unroll
  for (int i = 0; i < 4; ++i) acc[i] = 0.f;
  const short* wr = Wt + (192 + w * 16 + lrow) * 576;

  #pragma unroll
  for (int ks = 0; ks < 18; ++ks){
    const int kxy = ks >> 1;
    const int ky  = kxy / 3;
    const int kx  = kxy - ky * 3;
    const int ci0 = (ks & 1) << 5;
    const int yy  = y + ky - 1;
    const int xx  = xx0 + kx - 1;
    bf16x8 a = {0,0,0,0,0,0,0,0};
    if ((unsigned)yy < 64u && (unsigned)xx < 64u)
      a = *(const bf16x8*)(ab + ((((b << 6) + yy) << 6) + xx) * 64 + ci0 + lkb * 8);
    const bf16x8 w8 = *(const bf16x8*)(wr + ks * 32 + lkb * 8);
    acc = __builtin_amdgcn_mfma_f32_16x16x32_bf16(a, w8, acc, 0, 0, 0);
  }
  const int oc = w * 16 + lrow;
  const float bb = br[oc];
  #pragma unroll
  for (int i = 0; i < 4; ++i){
    const int p = p0 + (lkb << 2) + i;
    out[(size_t)p * 64 + oc] = fmaxf(acc[i] + bb, 0.f);
  }
}

extern "C" void kernel_launch(void* const* d_in, const int* in_sizes, int n_in,
                              void* d_out, int out_size, void* d_ws, size_t ws_size,
                              hipStream_t stream)
{
  const float* x  = (const float*)d_in[0];
  const float* Wk = (const float*)d_in[1];
  const float* bk = (const float*)d_in[2];
  const float* Wq = (const float*)d_in[3];
  const float* bq = (const float*)d_in[4];
  const float* Wv = (const float*)d_in[5];
  const float* bv = (const float*)d_in[6];
  const float* Wr = (const float*)d_in[7];
  const float* br = (const float*)d_in[8];
  float* out = (float*)d_out;

  const size_t BNF = (size_t)B_ * N_ * F_;          // 1,048,576
  const size_t fixed_shorts = BNF * 5 + 256 * 576;  // xb16, q, k, vt, attnb, Wt
  const size_t fixed_bytes  = fixed_shorts * 2;
  int split = 8;
  while (split > 1 &&
         fixed_bytes + (size_t)split * (BNF * 4 + (size_t)B_ * N_ * 4) > ws_size)
    split >>= 1;

  short* xb16 = (short*)d_ws;
  short* Wt   = xb16 + BNF;
  short* qw   = Wt + 256 * 576;
  short* kw   = qw + BNF;
  short* vt   = kw + BNF;
  short* attnb= vt + BNF;
  float* Op   = (float*)(attnb + BNF);
  float* lp   = Op + (size_t)split * BNF;

  hipLaunchKernelGGL(prep_x_kernel, dim3(1024), dim3(256), 0, stream, x, xb16);
  hipLaunchKernelGGL(prep_w_kernel, dim3(576), dim3(256), 0, stream, Wk, Wq, Wv, Wr, Wt);
  hipLaunchKernelGGL(conv_qkv_mfma, dim3(1024), dim3(256), 0, stream,
                     xb16, Wt, bk, bq, bv, qw, kw, vt);
  hipLaunchKernelGGL(attn_kernel, dim3(B_ * 32 * split), dim3(256), 0, stream,
                     qw, kw, vt, Op, lp, split);
  hipLaunchKernelGGL(combine_kernel, dim3((B_ * N_ * F_) / 256), dim3(256), 0, stream,
                     Op, lp, attnb, split);
  hipLaunchKernelGGL(conv_out_mfma, dim3(1024), dim3(256), 0, stream,
                     attnb, Wt, br, out);
}

// Round 10
// 99.400 us; speedup vs baseline: 3.3828x; 1.1368x over previous
//
#include <hip/hip_runtime.h>
#include <hip/hip_bf16.h>
#include <math.h>

#define B_ 4
#define H_ 64
#define W_ 64
#define C_ 64
#define F_ 64
#define N_ 4096

typedef __attribute__((ext_vector_type(8))) short bf16x8;
typedef __attribute__((ext_vector_type(4))) short bf16x4;
typedef __attribute__((ext_vector_type(4))) float f32x4;

static __device__ __forceinline__ short f2bf(float f){
  union { __hip_bfloat16 h; short s; } u;
  u.h = __float2bfloat16(f);
  return u.s;
}

// ---------------- prep: x fp32 -> bf16 ----------------
__global__ __launch_bounds__(256) void prep_x_kernel(
    const float* __restrict__ x, short* __restrict__ xb)
{
  const int i4 = blockIdx.x * 256 + threadIdx.x;   // over B*N*C/4
  const float4 v = ((const float4*)x)[i4];
  bf16x4 o;
  o[0] = f2bf(v.x); o[1] = f2bf(v.y); o[2] = f2bf(v.z); o[3] = f2bf(v.w);
  ((bf16x4*)xb)[i4] = o;
}

// ---------------- prep: weights HWIO fp32 -> Wt[256][576] bf16 ----------------
__global__ __launch_bounds__(256) void prep_w_kernel(
    const float* __restrict__ Wk, const float* __restrict__ Wq,
    const float* __restrict__ Wv, const float* __restrict__ Wr,
    short* __restrict__ Wt)
{
  const int gid = blockIdx.x * 256 + threadIdx.x;  // 256*576
  const int oc = gid / 576;
  const int kk = gid % 576;                        // (ky*3+kx)*64 + ci
  const int srcofs = (kk >> 6) * 4096 + (kk & 63) * 64 + (oc & 63);
  const float* src = (oc < 64) ? Wk : (oc < 128) ? Wq : (oc < 192) ? Wv : Wr;
  Wt[gid] = f2bf(src[srcofs]);
}

// ---------------- conv QKV as implicit-GEMM MFMA: 32 px/block, 2 M-subtiles/wave ----------------
// per K-step: 2 A-loads + 3 W-loads -> 6 MFMA (weights reused across both M-subtiles)
__global__ __launch_bounds__(256) void conv_qkv_mfma(
    const short* __restrict__ xb, const short* __restrict__ Wt,
    const float* __restrict__ bk, const float* __restrict__ bq,
    const float* __restrict__ bv,
    short* __restrict__ qo, short* __restrict__ ko, short* __restrict__ vt)
{
  const int lane = threadIdx.x & 63;
  const int w    = threadIdx.x >> 6;
  const int lrow = lane & 15;
  const int lkb  = lane >> 4;
  const int p0   = blockIdx.x << 5;      // 32 consecutive pixels (within one image row)
  const int b    = p0 >> 12;
  const int y    = (p0 >> 6) & 63;
  const int x0   = p0 & 63;              // 0 or 32

  f32x4 ak[2], aq[2], av[2];
  #pragma unroll
  for (int m = 0; m < 2; ++m)
    #pragma unroll
    for (int i = 0; i < 4; ++i){ ak[m][i] = 0.f; aq[m][i] = 0.f; av[m][i] = 0.f; }

  const short* wr_k = Wt + (      w * 16 + lrow) * 576;
  const short* wr_q = Wt + ( 64 + w * 16 + lrow) * 576;
  const short* wr_v = Wt + (128 + w * 16 + lrow) * 576;

  #pragma unroll
  for (int ks = 0; ks < 18; ++ks){
    const int kxy = ks >> 1;
    const int ky  = kxy / 3;
    const int kx  = kxy - ky * 3;
    const int ci0 = (ks & 1) << 5;
    const int yy  = y + ky - 1;
    const bf16x8 wk8 = *(const bf16x8*)(wr_k + ks * 32 + lkb * 8);
    const bf16x8 wq8 = *(const bf16x8*)(wr_q + ks * 32 + lkb * 8);
    const bf16x8 wv8 = *(const bf16x8*)(wr_v + ks * 32 + lkb * 8);
    #pragma unroll
    for (int m = 0; m < 2; ++m){
      const int xx = x0 + m * 16 + lrow + kx - 1;
      bf16x8 a = {0,0,0,0,0,0,0,0};
      if ((unsigned)yy < 64u && (unsigned)xx < 64u)
        a = *(const bf16x8*)(xb + ((((b << 6) + yy) << 6) + xx) * 64 + ci0 + lkb * 8);
      ak[m] = __builtin_amdgcn_mfma_f32_16x16x32_bf16(a, wk8, ak[m], 0, 0, 0);
      aq[m] = __builtin_amdgcn_mfma_f32_16x16x32_bf16(a, wq8, aq[m], 0, 0, 0);
      av[m] = __builtin_amdgcn_mfma_f32_16x16x32_bf16(a, wv8, av[m], 0, 0, 0);
    }
  }
  const int oc = w * 16 + lrow;
  const float bkv = bk[oc], bqv = bq[oc], bvv = bv[oc];
  #pragma unroll
  for (int m = 0; m < 2; ++m){
    bf16x4 vp;
    #pragma unroll
    for (int i = 0; i < 4; ++i){
      const int p = p0 + m * 16 + (lkb << 2) + i;
      const float kvv = ak[m][i] + bkv;
      ko[p * 64 + oc] = f2bf(kvv > 0.f ? kvv : expm1f(kvv));            // elu
      const float qvv = aq[m][i] + bqv;
      const float qe  = (qvv > 0.f ? qvv : expm1f(qvv)) * 0.125f;       // elu * 1/sqrt(F)
      qo[p * 64 + oc] = f2bf(qe);
      const float vvv = av[m][i] + bvv;
      vp[i] = f2bf(vvv > 0.f ? vvv : 0.f);                              // relu
    }
    *(bf16x4*)(vt + ((size_t)(b * 64 + oc)) * 4096 + (p0 & 4095) + m * 16 + (lkb << 2)) = vp;
  }
}

// ---------------- flash attention: 32 rows/wave, constant-m softmax, LDS-staged K/V ----------------
// UNCHANGED from round 9 (control).
__global__ __launch_bounds__(256, 3) void attn_kernel(
    const short* __restrict__ q, const short* __restrict__ k,
    const short* __restrict__ vt, float* __restrict__ Op,
    float* __restrict__ lp, int split)
{
  const int tid  = threadIdx.x;
  const int lane = tid & 63;
  const int wv   = tid >> 6;
  const int lrow = lane & 15;
  const int lkb  = lane >> 4;

  const int bid  = blockIdx.x;
  const int b    = bid / (32 * split);
  const int rem  = bid % (32 * split);
  const int rt   = rem / split;
  const int sp   = rem % split;
  const int rbase = (rt << 7) + (wv << 5);
  const int tiles = (N_ / 64) / split;
  const int ct0   = sp * tiles;

  const short* qb = q  + (size_t)b * N_ * F_;
  const short* kb = k  + (size_t)b * N_ * F_;
  const short* vb = vt + (size_t)b * F_ * N_;

  const bf16x8 aq00 = *(const bf16x8*)(qb + (rbase +      lrow) * F_ + lkb * 8);
  const bf16x8 aq01 = *(const bf16x8*)(qb + (rbase +      lrow) * F_ + 32 + lkb * 8);
  const bf16x8 aq10 = *(const bf16x8*)(qb + (rbase + 16 + lrow) * F_ + lkb * 8);
  const bf16x8 aq11 = *(const bf16x8*)(qb + (rbase + 16 + lrow) * F_ + 32 + lkb * 8);

  __shared__ short kbuf[2][64 * 64];
  __shared__ short vbuf[2][64 * 64];
  __shared__ short p_lds[4][2][16][72];

  const int srow = tid >> 3;
  const int sc16 = tid & 7;
  const int dst0 = (srow * 128)        + ((sc16 * 16) ^ ((srow & 7) << 4));
  const int dst1 = ((srow + 32) * 128) + ((sc16 * 16) ^ ((srow & 7) << 4));

  float l_r[2][4];
  f32x4 oacc[2][4];
  #pragma unroll
  for (int g = 0; g < 2; ++g){
    #pragma unroll
    for (int i = 0; i < 4; ++i) l_r[g][i] = 0.f;
    #pragma unroll
    for (int fs = 0; fs < 4; ++fs)
      #pragma unroll
      for (int i = 0; i < 4; ++i) oacc[g][fs][i] = 0.f;
  }

  int cbase = ct0 << 6;
  bf16x8 sk0 = *(const bf16x8*)(kb + (cbase + srow) * 64      + sc16 * 8);
  bf16x8 sk1 = *(const bf16x8*)(kb + (cbase + srow + 32) * 64 + sc16 * 8);
  bf16x8 sv0 = *(const bf16x8*)(vb + (size_t)srow * N_        + cbase + sc16 * 8);
  bf16x8 sv1 = *(const bf16x8*)(vb + (size_t)(srow + 32) * N_ + cbase + sc16 * 8);
  *(bf16x8*)((char*)kbuf[0] + dst0) = sk0;
  *(bf16x8*)((char*)kbuf[0] + dst1) = sk1;
  *(bf16x8*)((char*)vbuf[0] + dst0) = sv0;
  *(bf16x8*)((char*)vbuf[0] + dst1) = sv1;
  __syncthreads();

  int cur = 0;
  for (int t = 0; t < tiles; ++t){
    cbase = (ct0 + t) << 6;
    if (t + 1 < tiles){
      const int cb2 = (ct0 + t + 1) << 6;
      sk0 = *(const bf16x8*)(kb + (cb2 + srow) * 64      + sc16 * 8);
      sk1 = *(const bf16x8*)(kb + (cb2 + srow + 32) * 64 + sc16 * 8);
      sv0 = *(const bf16x8*)(vb + (size_t)srow * N_        + cb2 + sc16 * 8);
      sv1 = *(const bf16x8*)(vb + (size_t)(srow + 32) * N_ + cb2 + sc16 * 8);
    }
    const char* kc = (const char*)kbuf[cur];
    const char* vc = (const char*)vbuf[cur];
    f32x4 s0[4], s1[4];
    #pragma unroll
    for (int n = 0; n < 4; ++n){
      #pragma unroll
      for (int i = 0; i < 4; ++i){ s0[n][i] = 0.f; s1[n][i] = 0.f; }
    }
    #pragma unroll
    for (int n = 0; n < 4; ++n){
      const int r   = n * 16 + lrow;
      const int swz = (r & 7) << 4;
      const bf16x8 b0 = *(const bf16x8*)(kc + r * 128 + ((lkb * 16) ^ swz));
      const bf16x8 b1 = *(const bf16x8*)(kc + r * 128 + ((64 + lkb * 16) ^ swz));
      s0[n] = __builtin_amdgcn_mfma_f32_16x16x32_bf16(aq00, b0, s0[n], 0, 0, 0);
      s0[n] = __builtin_amdgcn_mfma_f32_16x16x32_bf16(aq01, b1, s0[n], 0, 0, 0);
      s1[n] = __builtin_amdgcn_mfma_f32_16x16x32_bf16(aq10, b0, s1[n], 0, 0, 0);
      s1[n] = __builtin_amdgcn_mfma_f32_16x16x32_bf16(aq11, b1, s1[n], 0, 0, 0);
    }
    #pragma unroll
    for (int g = 0; g < 2; ++g){
      f32x4* s = g ? s1 : s0;
      const int rb = rbase + g * 16 + lkb * 4;
      #pragma unroll
      for (int n = 0; n < 4; ++n){
        const int gc = cbase + n * 16 + lrow;
        #pragma unroll
        for (int i = 0; i < 4; ++i){
          float sv = s[n][i];
          if (rb + i == gc) sv = 0.f;
          const float p = exp2f(fmaf(sv, 1.44269504f, -23.0831206f));
          l_r[g][i] += p;
          p_lds[wv][g][lkb * 4 + i][n * 16 + lrow] = f2bf(p);
        }
      }
    }
    #pragma unroll
    for (int kc2 = 0; kc2 < 2; ++kc2){
      const bf16x8 pa0 = *(const bf16x8*)(&p_lds[wv][0][lrow][kc2 * 32 + lkb * 8]);
      const bf16x8 pa1 = *(const bf16x8*)(&p_lds[wv][1][lrow][kc2 * 32 + lkb * 8]);
      #pragma unroll
      for (int fs = 0; fs < 4; ++fs){
        const int r   = fs * 16 + lrow;
        const int swz = (r & 7) << 4;
        const bf16x8 bvf = *(const bf16x8*)(vc + r * 128 + ((kc2 * 64 + lkb * 16) ^ swz));
        oacc[0][fs] = __builtin_amdgcn_mfma_f32_16x16x32_bf16(pa0, bvf, oacc[0][fs], 0, 0, 0);
        oacc[1][fs] = __builtin_amdgcn_mfma_f32_16x16x32_bf16(pa1, bvf, oacc[1][fs], 0, 0, 0);
      }
    }
    __syncthreads();
    if (t + 1 < tiles){
      const int nxt = cur ^ 1;
      *(bf16x8*)((char*)kbuf[nxt] + dst0) = sk0;
      *(bf16x8*)((char*)kbuf[nxt] + dst1) = sk1;
      *(bf16x8*)((char*)vbuf[nxt] + dst0) = sv0;
      *(bf16x8*)((char*)vbuf[nxt] + dst1) = sv1;
    }
    __syncthreads();
    cur ^= 1;
  }
  float* Ob = Op + (size_t)(b * split + sp) * N_ * F_;
  #pragma unroll
  for (int g = 0; g < 2; ++g){
    #pragma unroll
    for (int i = 0; i < 4; ++i){
      #pragma unroll
      for (int d = 1; d < 16; d <<= 1)
        l_r[g][i] += __shfl_xor(l_r[g][i], d, 64);
      const int row = rbase + g * 16 + lkb * 4 + i;
      #pragma unroll
      for (int fs = 0; fs < 4; ++fs)
        Ob[(size_t)row * F_ + fs * 16 + lrow] = oacc[g][fs][i];
      if (lrow == 0)
        lp[(size_t)(b * split + sp) * N_ + row] = l_r[g][i];
    }
  }
}

// ---------------- combine partials (constant m) -> bf16 ----------------
__global__ __launch_bounds__(256) void combine_kernel(
    const float* __restrict__ Op, const float* __restrict__ lp,
    short* __restrict__ ob, int split)
{
  const int gid = blockIdx.x * 256 + threadIdx.x;
  const int f = gid & 63;
  const int n = (gid >> 6) & (N_ - 1);
  const int b = gid >> 18;
  float L = 0.f, O = 0.f;
  for (int s = 0; s < split; ++s){
    L += lp[(size_t)(b * split + s) * N_ + n];
    O += Op[((size_t)(b * split + s) * N_ + n) * F_ + f];
  }
  ob[gid] = f2bf(O / L);
}

// ---------------- final conv as implicit-GEMM MFMA: 32 px/block ----------------
__global__ __launch_bounds__(256) void conv_out_mfma(
    const short* __restrict__ ab, const short* __restrict__ Wt,
    const float* __restrict__ br, float* __restrict__ out)
{
  const int lane = threadIdx.x & 63;
  const int w    = threadIdx.x >> 6;
  const int lrow = lane & 15;
  const int lkb  = lane >> 4;
  const int p0   = blockIdx.x << 5;
  const int b    = p0 >> 12;
  const int y    = (p0 >> 6) & 63;
  const int x0   = p0 & 63;

  f32x4 acc[2];
  #pragma unroll
  for (int m = 0; m < 2; ++m)
    #pragma unroll
    for (int i = 0; i < 4; ++i) acc[m][i] = 0.f;
  const short* wr = Wt + (192 + w * 16 + lrow) * 576;

  #pragma unroll
  for (int ks = 0; ks < 18; ++ks){
    const int kxy = ks >> 1;
    const int ky  = kxy / 3;
    const int kx  = kxy - ky * 3;
    const int ci0 = (ks & 1) << 5;
    const int yy  = y + ky - 1;
    const bf16x8 w8 = *(const bf16x8*)(wr + ks * 32 + lkb * 8);
    #pragma unroll
    for (int m = 0; m < 2; ++m){
      const int xx = x0 + m * 16 + lrow + kx - 1;
      bf16x8 a = {0,0,0,0,0,0,0,0};
      if ((unsigned)yy < 64u && (unsigned)xx < 64u)
        a = *(const bf16x8*)(ab + ((((b << 6) + yy) << 6) + xx) * 64 + ci0 + lkb * 8);
      acc[m] = __builtin_amdgcn_mfma_f32_16x16x32_bf16(a, w8, acc[m], 0, 0, 0);
    }
  }
  const int oc = w * 16 + lrow;
  const float bb = br[oc];
  #pragma unroll
  for (int m = 0; m < 2; ++m)
    #pragma unroll
    for (int i = 0; i < 4; ++i){
      const int p = p0 + m * 16 + (lkb << 2) + i;
      out[(size_t)p * 64 + oc] = fmaxf(acc[m][i] + bb, 0.f);
    }
}

extern "C" void kernel_launch(void* const* d_in, const int* in_sizes, int n_in,
                              void* d_out, int out_size, void* d_ws, size_t ws_size,
                              hipStream_t stream)
{
  const float* x  = (const float*)d_in[0];
  const float* Wk = (const float*)d_in[1];
  const float* bk = (const float*)d_in[2];
  const float* Wq = (const float*)d_in[3];
  const float* bq = (const float*)d_in[4];
  const float* Wv = (const float*)d_in[5];
  const float* bv = (const float*)d_in[6];
  const float* Wr = (const float*)d_in[7];
  const float* br = (const float*)d_in[8];
  float* out = (float*)d_out;

  const size_t BNF = (size_t)B_ * N_ * F_;
  const size_t fixed_shorts = BNF * 5 + 256 * 576;
  const size_t fixed_bytes  = fixed_shorts * 2;
  int split = 8;
  while (split > 1 &&
         fixed_bytes + (size_t)split * (BNF * 4 + (size_t)B_ * N_ * 4) > ws_size)
    split >>= 1;

  short* xb16 = (short*)d_ws;
  short* Wt   = xb16 + BNF;
  short* qw   = Wt + 256 * 576;
  short* kw   = qw + BNF;
  short* vt   = kw + BNF;
  short* attnb= vt + BNF;
  float* Op   = (float*)(attnb + BNF);
  float* lp   = Op + (size_t)split * BNF;

  hipLaunchKernelGGL(prep_x_kernel, dim3(1024), dim3(256), 0, stream, x, xb16);
  hipLaunchKernelGGL(prep_w_kernel, dim3(576), dim3(256), 0, stream, Wk, Wq, Wv, Wr, Wt);
  hipLaunchKernelGGL(conv_qkv_mfma, dim3(512), dim3(256), 0, stream,
                     xb16, Wt, bk, bq, bv, qw, kw, vt);
  hipLaunchKernelGGL(attn_kernel, dim3(B_ * 32 * split), dim3(256), 0, stream,
                     qw, kw, vt, Op, lp, split);
  hipLaunchKernelGGL(combine_kernel, dim3((B_ * N_ * F_) / 256), dim3(256), 0, stream,
                     Op, lp, attnb, split);
  hipLaunchKernelGGL(conv_out_mfma, dim3(512), dim3(256), 0, stream,
                     attnb, Wt, br, out);
}